// Round 17
// baseline (320.289 us; speedup 1.0000x reference)
//
#include <hip/hip_runtime.h>
#include <math.h>

#define B_ 8
#define T_ 1024
#define S_ 1024
#define D_ 256
#define H_ 4
#define DH_ 64
#define AUDIO_ 768
#define MOTION_ 33
#define PERIOD_ 30
#define WIN_ 4
#define M_ (B_ * T_)
#define PART_ (B_ * H_ * T_)   // 32768 partial rows per half

typedef _Float16 half8 __attribute__((ext_vector_type(8)));
typedef _Float16 half4 __attribute__((ext_vector_type(4)));
typedef __attribute__((ext_vector_type(4))) float f32x4;

// fp16 weight arena offsets (halves)
#define O_AF    0
#define O_SAIN  196608   // + l*196608
#define O_SAOUT 589824   // + l*65536
#define O_CAIN  720896   // + l*196608
#define O_CAOUT 1114112  // + l*65536
#define O_FF1   1245184  // + l*131072
#define O_FF2   1507328  // + l*131072
#define O_CONV1 1769472
#define O_CONV2 2097152
#define O_VR    2424832  // W_vr padded to 64x256
#define WH_TOT  2441216  // divisible by 256 -> exact grid

struct CvtSrc { const float* p[17]; };

// ---------------------------------------------------------------------------
// One-shot fp32->fp16 conversion of all weights (+ conv repack, + W_vr pad).
// ---------------------------------------------------------------------------
__global__ __launch_bounds__(256) void cvt_all(
    CvtSrc s, _Float16* __restrict__ wH) {
  const long i = (long)blockIdx.x * 256 + threadIdx.x;
  if (i >= WH_TOT) return;
  if (i >= O_VR) {
    const long j = i - O_VR, oc = j >> 8, cin = j & 255;
    wH[i] = (oc < MOTION_) ? (_Float16)s.p[16][oc * 256 + cin] : (_Float16)0.f;
    return;
  }
  if (i >= O_CONV2) {
    const long j = i - O_CONV2, oc = j / 1280, r = j % 1280, tap = r >> 8, cin = r & 255;
    wH[i] = (_Float16)s.p[14][(oc * 256 + cin) * 5 + tap]; return;
  }
  if (i >= O_CONV1) {
    const long j = i - O_CONV1, oc = j / 1280, r = j % 1280, tap = r >> 8, cin = r & 255;
    wH[i] = (_Float16)s.p[13][(oc * 256 + cin) * 5 + tap]; return;
  }
  int seg; long base;
  if      (i >= 1638400) { seg = 12; base = 1638400; }
  else if (i >= 1507328) { seg = 11; base = 1507328; }
  else if (i >= 1376256) { seg = 10; base = 1376256; }
  else if (i >= 1245184) { seg = 9;  base = 1245184; }
  else if (i >= 1179648) { seg = 8;  base = 1179648; }
  else if (i >= 1114112) { seg = 7;  base = 1114112; }
  else if (i >= 917504)  { seg = 6;  base = 917504; }
  else if (i >= 720896)  { seg = 5;  base = 720896; }
  else if (i >= 655360)  { seg = 4;  base = 655360; }
  else if (i >= 589824)  { seg = 3;  base = 589824; }
  else if (i >= 393216)  { seg = 2;  base = 393216; }
  else if (i >= 196608)  { seg = 1;  base = 196608; }
  else                   { seg = 0;  base = 0; }
  wH[i] = (_Float16)s.p[seg][i - base];
}

// ---------------------------------------------------------------------------
// fp16 GEMM: C = A @ W.T + bias (+ optional fp16 residual, + optional relu).
// Tile 64x64, BK=64, LDS double-buffer, one barrier per K-step.
// ---------------------------------------------------------------------------
__global__ __launch_bounds__(256) void gemm_h(
    const _Float16* __restrict__ A, const _Float16* __restrict__ W,
    const float* __restrict__ bias, const _Float16* __restrict__ ResH,
    _Float16* __restrict__ Ch, int M, int N, int K, int relu) {
  __shared__ _Float16 As[2][64][72];
  __shared__ _Float16 Bs[2][64][72];
  const int tid = threadIdx.x;
  const int wave = tid >> 6, lane = tid & 63;
  const int wr = wave >> 1, wc = wave & 1;
  const int lr16 = lane & 15, kq = lane >> 4;
  const int bm = blockIdx.x, bn = blockIdx.y;
  const int sr = tid >> 2, sq = tid & 3;

  const _Float16* Ap = A + (size_t)(bm * 64 + sr) * K + sq * 8;
  const _Float16* Wp = W + (size_t)(bn * 64 + sr) * K + sq * 8;

  half8 ra0 = *reinterpret_cast<const half8*>(Ap);
  half8 ra1 = *reinterpret_cast<const half8*>(Ap + 32);
  half8 rw0 = *reinterpret_cast<const half8*>(Wp);
  half8 rw1 = *reinterpret_cast<const half8*>(Wp + 32);
  f32x4 acc[2][2] = {};

  *reinterpret_cast<half8*>(&As[0][sr][sq * 8]) = ra0;
  *reinterpret_cast<half8*>(&As[0][sr][32 + sq * 8]) = ra1;
  *reinterpret_cast<half8*>(&Bs[0][sr][sq * 8]) = rw0;
  *reinterpret_cast<half8*>(&Bs[0][sr][32 + sq * 8]) = rw1;
  __syncthreads();

  const int nsteps = K >> 6;
  for (int step = 0; step < nsteps; ++step) {
    const int cur = step & 1;
    const bool more = (step + 1 < nsteps);
    if (more) {
      const int kn = (step + 1) << 6;
      ra0 = *reinterpret_cast<const half8*>(Ap + kn);
      ra1 = *reinterpret_cast<const half8*>(Ap + kn + 32);
      rw0 = *reinterpret_cast<const half8*>(Wp + kn);
      rw1 = *reinterpret_cast<const half8*>(Wp + kn + 32);
    }
    half8 af[2][2], bf[2][2];
#pragma unroll
    for (int m = 0; m < 2; ++m)
#pragma unroll
      for (int s = 0; s < 2; ++s)
        af[m][s] = *reinterpret_cast<const half8*>(
            &As[cur][wr * 32 + m * 16 + lr16][s * 32 + kq * 8]);
#pragma unroll
    for (int n = 0; n < 2; ++n)
#pragma unroll
      for (int s = 0; s < 2; ++s)
        bf[n][s] = *reinterpret_cast<const half8*>(
            &Bs[cur][wc * 32 + n * 16 + lr16][s * 32 + kq * 8]);
#pragma unroll
    for (int m = 0; m < 2; ++m)
#pragma unroll
      for (int n = 0; n < 2; ++n)
#pragma unroll
        for (int s = 0; s < 2; ++s)
          acc[m][n] = __builtin_amdgcn_mfma_f32_16x16x32_f16(af[m][s], bf[n][s], acc[m][n], 0, 0, 0);
    if (more) {
      *reinterpret_cast<half8*>(&As[cur ^ 1][sr][sq * 8]) = ra0;
      *reinterpret_cast<half8*>(&As[cur ^ 1][sr][32 + sq * 8]) = ra1;
      *reinterpret_cast<half8*>(&Bs[cur ^ 1][sr][sq * 8]) = rw0;
      *reinterpret_cast<half8*>(&Bs[cur ^ 1][sr][32 + sq * 8]) = rw1;
      __syncthreads();
    }
  }

#pragma unroll
  for (int m = 0; m < 2; ++m) {
#pragma unroll
    for (int n = 0; n < 2; ++n) {
      const int col = bn * 64 + wc * 32 + n * 16 + lr16;
      const float bv = bias[col];
#pragma unroll
      for (int j = 0; j < 4; ++j) {
        const int row = bm * 64 + wr * 32 + m * 16 + kq * 4 + j;
        float v = acc[m][n][j] + bv;
        if (relu) v = fmaxf(v, 0.f);
        const size_t idx = (size_t)row * N + col;
        if (ResH) v += (float)ResH[idx];
        Ch[idx] = (_Float16)v;
      }
    }
  }
}

// ---------------------------------------------------------------------------
// Audio front-end GEMM with fp32 A (converts in staging regs).
// ---------------------------------------------------------------------------
__global__ __launch_bounds__(256) void gemm_af(
    const float* __restrict__ A, const _Float16* __restrict__ W,
    const float* __restrict__ bias, _Float16* __restrict__ Ch,
    int M, int N, int K) {
  __shared__ _Float16 As[2][64][72];
  __shared__ _Float16 Bs[2][64][72];
  const int tid = threadIdx.x;
  const int wave = tid >> 6, lane = tid & 63;
  const int wr = wave >> 1, wc = wave & 1;
  const int lr16 = lane & 15, kq = lane >> 4;
  const int bm = blockIdx.x, bn = blockIdx.y;
  const int sr = tid >> 2, sq = tid & 3;

  const float* Ap = A + (size_t)(bm * 64 + sr) * K + sq * 8;
  const _Float16* Wp = W + (size_t)(bn * 64 + sr) * K + sq * 8;

  float4 fa0, fa1, fa2, fa3;
  half8 rw0, rw1;
  fa0 = *reinterpret_cast<const float4*>(Ap);
  fa1 = *reinterpret_cast<const float4*>(Ap + 4);
  fa2 = *reinterpret_cast<const float4*>(Ap + 32);
  fa3 = *reinterpret_cast<const float4*>(Ap + 36);
  rw0 = *reinterpret_cast<const half8*>(Wp);
  rw1 = *reinterpret_cast<const half8*>(Wp + 32);
  f32x4 acc[2][2] = {};

  {
    half8 pa0, pa1;
    pa0[0] = (_Float16)fa0.x; pa0[1] = (_Float16)fa0.y; pa0[2] = (_Float16)fa0.z; pa0[3] = (_Float16)fa0.w;
    pa0[4] = (_Float16)fa1.x; pa0[5] = (_Float16)fa1.y; pa0[6] = (_Float16)fa1.z; pa0[7] = (_Float16)fa1.w;
    pa1[0] = (_Float16)fa2.x; pa1[1] = (_Float16)fa2.y; pa1[2] = (_Float16)fa2.z; pa1[3] = (_Float16)fa2.w;
    pa1[4] = (_Float16)fa3.x; pa1[5] = (_Float16)fa3.y; pa1[6] = (_Float16)fa3.z; pa1[7] = (_Float16)fa3.w;
    *reinterpret_cast<half8*>(&As[0][sr][sq * 8]) = pa0;
    *reinterpret_cast<half8*>(&As[0][sr][32 + sq * 8]) = pa1;
    *reinterpret_cast<half8*>(&Bs[0][sr][sq * 8]) = rw0;
    *reinterpret_cast<half8*>(&Bs[0][sr][32 + sq * 8]) = rw1;
  }
  __syncthreads();

  const int nsteps = K >> 6;
  for (int step = 0; step < nsteps; ++step) {
    const int cur = step & 1;
    const bool more = (step + 1 < nsteps);
    if (more) {
      const int kn = (step + 1) << 6;
      fa0 = *reinterpret_cast<const float4*>(Ap + kn);
      fa1 = *reinterpret_cast<const float4*>(Ap + kn + 4);
      fa2 = *reinterpret_cast<const float4*>(Ap + kn + 32);
      fa3 = *reinterpret_cast<const float4*>(Ap + kn + 36);
      rw0 = *reinterpret_cast<const half8*>(Wp + kn);
      rw1 = *reinterpret_cast<const half8*>(Wp + kn + 32);
    }
    half8 af[2][2], bf[2][2];
#pragma unroll
    for (int m = 0; m < 2; ++m)
#pragma unroll
      for (int s = 0; s < 2; ++s)
        af[m][s] = *reinterpret_cast<const half8*>(
            &As[cur][wr * 32 + m * 16 + lr16][s * 32 + kq * 8]);
#pragma unroll
    for (int n = 0; n < 2; ++n)
#pragma unroll
      for (int s = 0; s < 2; ++s)
        bf[n][s] = *reinterpret_cast<const half8*>(
            &Bs[cur][wc * 32 + n * 16 + lr16][s * 32 + kq * 8]);
#pragma unroll
    for (int m = 0; m < 2; ++m)
#pragma unroll
      for (int n = 0; n < 2; ++n)
#pragma unroll
        for (int s = 0; s < 2; ++s)
          acc[m][n] = __builtin_amdgcn_mfma_f32_16x16x32_f16(af[m][s], bf[n][s], acc[m][n], 0, 0, 0);
    if (more) {
      half8 pa0, pa1;
      pa0[0] = (_Float16)fa0.x; pa0[1] = (_Float16)fa0.y; pa0[2] = (_Float16)fa0.z; pa0[3] = (_Float16)fa0.w;
      pa0[4] = (_Float16)fa1.x; pa0[5] = (_Float16)fa1.y; pa0[6] = (_Float16)fa1.z; pa0[7] = (_Float16)fa1.w;
      pa1[0] = (_Float16)fa2.x; pa1[1] = (_Float16)fa2.y; pa1[2] = (_Float16)fa2.z; pa1[3] = (_Float16)fa2.w;
      pa1[4] = (_Float16)fa3.x; pa1[5] = (_Float16)fa3.y; pa1[6] = (_Float16)fa3.z; pa1[7] = (_Float16)fa3.w;
      *reinterpret_cast<half8*>(&As[cur ^ 1][sr][sq * 8]) = pa0;
      *reinterpret_cast<half8*>(&As[cur ^ 1][sr][32 + sq * 8]) = pa1;
      *reinterpret_cast<half8*>(&Bs[cur ^ 1][sr][sq * 8]) = rw0;
      *reinterpret_cast<half8*>(&Bs[cur ^ 1][sr][32 + sq * 8]) = rw1;
      __syncthreads();
    }
  }

#pragma unroll
  for (int m = 0; m < 2; ++m) {
#pragma unroll
    for (int n = 0; n < 2; ++n) {
      const int col = bn * 64 + wc * 32 + n * 16 + lr16;
      const float bv = bias[col];
#pragma unroll
      for (int j = 0; j < 4; ++j) {
        const int row = bm * 64 + wr * 32 + m * 16 + kq * 4 + j;
        Ch[(size_t)row * N + col] = (_Float16)(acc[m][n][j] + bv);
      }
    }
  }
}

// ---------------------------------------------------------------------------
// SA out-projection with fused split-K merge (+ fp16 residual in epilogue).
// ---------------------------------------------------------------------------
struct SaPre {
  float4 h0a, h0b, h0c, h0d;
  float4 h1a, h1b, h1c, h1d;
  float m0, m1, l0, l1;
};

__device__ __forceinline__ SaPre sa_load(
    const float* __restrict__ Opart, const float* __restrict__ Ml,
    const float* __restrict__ Ll, size_t p, int sq) {
  SaPre x;
  const float* o0 = Opart + p * 64;
  const float* o1 = Opart + (size_t)PART_ * 64 + p * 64;
  x.h0a = *reinterpret_cast<const float4*>(o0 + sq * 8);
  x.h0b = *reinterpret_cast<const float4*>(o0 + sq * 8 + 4);
  x.h0c = *reinterpret_cast<const float4*>(o0 + 32 + sq * 8);
  x.h0d = *reinterpret_cast<const float4*>(o0 + 36 + sq * 8);
  x.h1a = *reinterpret_cast<const float4*>(o1 + sq * 8);
  x.h1b = *reinterpret_cast<const float4*>(o1 + sq * 8 + 4);
  x.h1c = *reinterpret_cast<const float4*>(o1 + 32 + sq * 8);
  x.h1d = *reinterpret_cast<const float4*>(o1 + 36 + sq * 8);
  x.m0 = Ml[p]; x.m1 = Ml[(size_t)PART_ + p];
  x.l0 = Ll[p]; x.l1 = Ll[(size_t)PART_ + p];
  return x;
}

__device__ __forceinline__ void sa_write(
    _Float16* dst0, _Float16* dst1, const SaPre& x) {
  const float m = fmaxf(x.m0, x.m1);
  const float w0 = __expf(x.m0 - m), w1 = __expf(x.m1 - m);
  const float inv = 1.f / (x.l0 * w0 + x.l1 * w1);
  const float g0h0[8] = {x.h0a.x, x.h0a.y, x.h0a.z, x.h0a.w,
                         x.h0b.x, x.h0b.y, x.h0b.z, x.h0b.w};
  const float g0h1[8] = {x.h1a.x, x.h1a.y, x.h1a.z, x.h1a.w,
                         x.h1b.x, x.h1b.y, x.h1b.z, x.h1b.w};
  const float g1h0[8] = {x.h0c.x, x.h0c.y, x.h0c.z, x.h0c.w,
                         x.h0d.x, x.h0d.y, x.h0d.z, x.h0d.w};
  const float g1h1[8] = {x.h1c.x, x.h1c.y, x.h1c.z, x.h1c.w,
                         x.h1d.x, x.h1d.y, x.h1d.z, x.h1d.w};
  half8 pa, pb;
#pragma unroll
  for (int e = 0; e < 8; ++e) {
    pa[e] = (_Float16)((g0h0[e] * w0 + g0h1[e] * w1) * inv);
    pb[e] = (_Float16)((g1h0[e] * w0 + g1h1[e] * w1) * inv);
  }
  *reinterpret_cast<half8*>(dst0) = pa;
  *reinterpret_cast<half8*>(dst1) = pb;
}

__global__ __launch_bounds__(256) void gemm_sa(
    const float* __restrict__ Opart, const float* __restrict__ Ml,
    const float* __restrict__ Ll, const _Float16* __restrict__ W,
    const float* __restrict__ bias, const _Float16* __restrict__ ResH,
    _Float16* __restrict__ Ch) {
  __shared__ _Float16 As[2][64][72];
  __shared__ _Float16 Bs[2][64][72];
  const int tid = threadIdx.x;
  const int wave = tid >> 6, lane = tid & 63;
  const int wr = wave >> 1, wc = wave & 1;
  const int lr16 = lane & 15, kq = lane >> 4;
  const int bm = blockIdx.x, bn = blockIdx.y;
  const int sr = tid >> 2, sq = tid & 3;

  const int r = bm * 64 + sr;
  const size_t pb0 = (size_t)(r >> 10) * 4096 + (r & 1023);
  const _Float16* Wp = W + (size_t)(bn * 64 + sr) * 256 + sq * 8;

  SaPre ax = sa_load(Opart, Ml, Ll, pb0, sq);
  half8 rw0 = *reinterpret_cast<const half8*>(Wp);
  half8 rw1 = *reinterpret_cast<const half8*>(Wp + 32);
  f32x4 acc[2][2] = {};

  sa_write(&As[0][sr][sq * 8], &As[0][sr][32 + sq * 8], ax);
  *reinterpret_cast<half8*>(&Bs[0][sr][sq * 8]) = rw0;
  *reinterpret_cast<half8*>(&Bs[0][sr][32 + sq * 8]) = rw1;
  __syncthreads();

  for (int step = 0; step < 4; ++step) {
    const int cur = step & 1;
    const bool more = (step + 1 < 4);
    if (more) {
      ax = sa_load(Opart, Ml, Ll, pb0 + (size_t)(step + 1) * 1024, sq);
      const int kn = (step + 1) << 6;
      rw0 = *reinterpret_cast<const half8*>(Wp + kn);
      rw1 = *reinterpret_cast<const half8*>(Wp + kn + 32);
    }
    half8 af[2][2], bf[2][2];
#pragma unroll
    for (int m = 0; m < 2; ++m)
#pragma unroll
      for (int s = 0; s < 2; ++s)
        af[m][s] = *reinterpret_cast<const half8*>(
            &As[cur][wr * 32 + m * 16 + lr16][s * 32 + kq * 8]);
#pragma unroll
    for (int n = 0; n < 2; ++n)
#pragma unroll
      for (int s = 0; s < 2; ++s)
        bf[n][s] = *reinterpret_cast<const half8*>(
            &Bs[cur][wc * 32 + n * 16 + lr16][s * 32 + kq * 8]);
#pragma unroll
    for (int m = 0; m < 2; ++m)
#pragma unroll
      for (int n = 0; n < 2; ++n)
#pragma unroll
        for (int s = 0; s < 2; ++s)
          acc[m][n] = __builtin_amdgcn_mfma_f32_16x16x32_f16(af[m][s], bf[n][s], acc[m][n], 0, 0, 0);
    if (more) {
      sa_write(&As[cur ^ 1][sr][sq * 8], &As[cur ^ 1][sr][32 + sq * 8], ax);
      *reinterpret_cast<half8*>(&Bs[cur ^ 1][sr][sq * 8]) = rw0;
      *reinterpret_cast<half8*>(&Bs[cur ^ 1][sr][32 + sq * 8]) = rw1;
      __syncthreads();
    }
  }

#pragma unroll
  for (int m = 0; m < 2; ++m) {
#pragma unroll
    for (int n = 0; n < 2; ++n) {
      const int col = bn * 64 + wc * 32 + n * 16 + lr16;
      const float bv = bias[col];
#pragma unroll
      for (int j = 0; j < 4; ++j) {
        const int row = bm * 64 + wr * 32 + m * 16 + kq * 4 + j;
        const size_t idx = (size_t)row * 256 + col;
        Ch[idx] = (_Float16)(acc[m][n][j] + bv + (float)ResH[idx]);
      }
    }
  }
}

// ---------------------------------------------------------------------------
// Merged cross-attention projections: one dispatch, grid (M/64, 12).
// ---------------------------------------------------------------------------
__global__ __launch_bounds__(256) void gemm_ca(
    const _Float16* __restrict__ Aq, const _Float16* __restrict__ Akv,
    const _Float16* __restrict__ W, const float* __restrict__ bias,
    _Float16* __restrict__ Oq, _Float16* __restrict__ Okv) {
  __shared__ _Float16 As[2][64][72];
  __shared__ _Float16 Bs[2][64][72];
  const int tid = threadIdx.x;
  const int wave = tid >> 6, lane = tid & 63;
  const int wr = wave >> 1, wc = wave & 1;
  const int lr16 = lane & 15, kq = lane >> 4;
  const int bm = blockIdx.x, bn = blockIdx.y;
  const int sr = tid >> 2, sq = tid & 3;
  const bool isq = (bn < 4);
  const _Float16* A = isq ? Aq : Akv;
  _Float16* Optr = isq ? Oq : Okv;
  const int Nout = isq ? 256 : 512;
  const int ocol0 = (isq ? bn : bn - 4) * 64;

  const _Float16* Ap = A + (size_t)(bm * 64 + sr) * 256 + sq * 8;
  const _Float16* Wp = W + (size_t)(bn * 64 + sr) * 256 + sq * 8;

  half8 ra0 = *reinterpret_cast<const half8*>(Ap);
  half8 ra1 = *reinterpret_cast<const half8*>(Ap + 32);
  half8 rw0 = *reinterpret_cast<const half8*>(Wp);
  half8 rw1 = *reinterpret_cast<const half8*>(Wp + 32);
  f32x4 acc[2][2] = {};

  *reinterpret_cast<half8*>(&As[0][sr][sq * 8]) = ra0;
  *reinterpret_cast<half8*>(&As[0][sr][32 + sq * 8]) = ra1;
  *reinterpret_cast<half8*>(&Bs[0][sr][sq * 8]) = rw0;
  *reinterpret_cast<half8*>(&Bs[0][sr][32 + sq * 8]) = rw1;
  __syncthreads();

  for (int step = 0; step < 4; ++step) {
    const int cur = step & 1;
    const bool more = (step + 1 < 4);
    if (more) {
      const int kn = (step + 1) << 6;
      ra0 = *reinterpret_cast<const half8*>(Ap + kn);
      ra1 = *reinterpret_cast<const half8*>(Ap + kn + 32);
      rw0 = *reinterpret_cast<const half8*>(Wp + kn);
      rw1 = *reinterpret_cast<const half8*>(Wp + kn + 32);
    }
    half8 af[2][2], bf[2][2];
#pragma unroll
    for (int m = 0; m < 2; ++m)
#pragma unroll
      for (int s = 0; s < 2; ++s)
        af[m][s] = *reinterpret_cast<const half8*>(
            &As[cur][wr * 32 + m * 16 + lr16][s * 32 + kq * 8]);
#pragma unroll
    for (int n = 0; n < 2; ++n)
#pragma unroll
      for (int s = 0; s < 2; ++s)
        bf[n][s] = *reinterpret_cast<const half8*>(
            &Bs[cur][wc * 32 + n * 16 + lr16][s * 32 + kq * 8]);
#pragma unroll
    for (int m = 0; m < 2; ++m)
#pragma unroll
      for (int n = 0; n < 2; ++n)
#pragma unroll
        for (int s = 0; s < 2; ++s)
          acc[m][n] = __builtin_amdgcn_mfma_f32_16x16x32_f16(af[m][s], bf[n][s], acc[m][n], 0, 0, 0);
    if (more) {
      *reinterpret_cast<half8*>(&As[cur ^ 1][sr][sq * 8]) = ra0;
      *reinterpret_cast<half8*>(&As[cur ^ 1][sr][32 + sq * 8]) = ra1;
      *reinterpret_cast<half8*>(&Bs[cur ^ 1][sr][sq * 8]) = rw0;
      *reinterpret_cast<half8*>(&Bs[cur ^ 1][sr][32 + sq * 8]) = rw1;
      __syncthreads();
    }
  }

#pragma unroll
  for (int m = 0; m < 2; ++m) {
#pragma unroll
    for (int n = 0; n < 2; ++n) {
      const int lc = wc * 32 + n * 16 + lr16;
      const float bv = bias[bn * 64 + lc];
#pragma unroll
      for (int j = 0; j < 4; ++j) {
        const int row = bm * 64 + wr * 32 + m * 16 + kq * 4 + j;
        Optr[(size_t)row * Nout + ocol0 + lc] = (_Float16)(acc[m][n][j] + bv);
      }
    }
  }
}

// ---------------------------------------------------------------------------
// Conv1d k=5 as fp16 GEMM, K=1280 tap-major repacked weights, BK=64, dbuf.
// ---------------------------------------------------------------------------
__device__ __forceinline__ half8 conv_ld(const _Float16* Xb, int p, int tap, int cin) {
  const int sp = p + tap - 2;
  if (sp < 0 || sp >= S_) { half8 z = {}; return z; }
  return *reinterpret_cast<const half8*>(Xb + (size_t)sp * D_ + cin);
}

__global__ __launch_bounds__(256) void conv_h(
    const _Float16* __restrict__ Xh, const _Float16* __restrict__ Wc,
    const float* __restrict__ bias, _Float16* OutH,
    const _Float16* ResH, int mode) {
  __shared__ _Float16 As[2][64][72];
  __shared__ _Float16 Bs[2][64][72];
  const int tid = threadIdx.x;
  const int wave = tid >> 6, lane = tid & 63;
  const int wr = wave >> 1, wc = wave & 1;
  const int lr16 = lane & 15, kq = lane >> 4;
  const int b = blockIdx.x >> 4;
  const int s0 = (blockIdx.x & 15) * 64;
  const int o0 = blockIdx.y * 64;
  const int sr = tid >> 2, sq = tid & 3;

  const _Float16* Xb = Xh + (size_t)b * S_ * D_;
  const _Float16* Wp = Wc + (size_t)(o0 + sr) * 1280 + sq * 8;
  const int p = s0 + sr;

  half8 ra0 = conv_ld(Xb, p, 0, sq * 8);
  half8 ra1 = conv_ld(Xb, p, 0, 32 + sq * 8);
  half8 rw0 = *reinterpret_cast<const half8*>(Wp);
  half8 rw1 = *reinterpret_cast<const half8*>(Wp + 32);
  f32x4 acc[2][2] = {};

  *reinterpret_cast<half8*>(&As[0][sr][sq * 8]) = ra0;
  *reinterpret_cast<half8*>(&As[0][sr][32 + sq * 8]) = ra1;
  *reinterpret_cast<half8*>(&Bs[0][sr][sq * 8]) = rw0;
  *reinterpret_cast<half8*>(&Bs[0][sr][32 + sq * 8]) = rw1;
  __syncthreads();

  for (int step = 0; step < 20; ++step) {
    const int cur = step & 1;
    const bool more = (step + 1 < 20);
    if (more) {
      const int kn = (step + 1) << 6;
      const int tap = kn >> 8, cb = kn & 255;
      ra0 = conv_ld(Xb, p, tap, cb + sq * 8);
      ra1 = conv_ld(Xb, p, tap, cb + 32 + sq * 8);
      rw0 = *reinterpret_cast<const half8*>(Wp + kn);
      rw1 = *reinterpret_cast<const half8*>(Wp + kn + 32);
    }
    half8 af[2][2], bf[2][2];
#pragma unroll
    for (int m = 0; m < 2; ++m)
#pragma unroll
      for (int s = 0; s < 2; ++s)
        af[m][s] = *reinterpret_cast<const half8*>(
            &As[cur][wr * 32 + m * 16 + lr16][s * 32 + kq * 8]);
#pragma unroll
    for (int n = 0; n < 2; ++n)
#pragma unroll
      for (int s = 0; s < 2; ++s)
        bf[n][s] = *reinterpret_cast<const half8*>(
            &Bs[cur][wc * 32 + n * 16 + lr16][s * 32 + kq * 8]);
#pragma unroll
    for (int m = 0; m < 2; ++m)
#pragma unroll
      for (int n = 0; n < 2; ++n)
#pragma unroll
        for (int s = 0; s < 2; ++s)
          acc[m][n] = __builtin_amdgcn_mfma_f32_16x16x32_f16(af[m][s], bf[n][s], acc[m][n], 0, 0, 0);
    if (more) {
      *reinterpret_cast<half8*>(&As[cur ^ 1][sr][sq * 8]) = ra0;
      *reinterpret_cast<half8*>(&As[cur ^ 1][sr][32 + sq * 8]) = ra1;
      *reinterpret_cast<half8*>(&Bs[cur ^ 1][sr][sq * 8]) = rw0;
      *reinterpret_cast<half8*>(&Bs[cur ^ 1][sr][32 + sq * 8]) = rw1;
      __syncthreads();
    }
  }

#pragma unroll
  for (int m = 0; m < 2; ++m) {
#pragma unroll
    for (int n = 0; n < 2; ++n) {
      const int oc = o0 + wc * 32 + n * 16 + lr16;
      const float bv = bias[oc];
#pragma unroll
      for (int j = 0; j < 4; ++j) {
        const int s = s0 + wr * 32 + m * 16 + kq * 4 + j;
        const size_t idx = ((size_t)b * S_ + s) * D_ + oc;
        float v = acc[m][n][j] + bv;
        if (mode == 0) {
          v = 0.5f * v * (1.f + erff(v * 0.70710678118654752f));
        } else {
          v += (float)ResH[idx];
        }
        OutH[idx] = (_Float16)v;
      }
    }
  }
}

// ---------------------------------------------------------------------------
// Head: out = clip(x @ W_vr.T + b_vr, 0, 1) via MFMA (W_vr padded to 64).
// ---------------------------------------------------------------------------
__global__ __launch_bounds__(256) void head_mfma(
    const _Float16* __restrict__ Xh, const _Float16* __restrict__ Wh,
    const float* __restrict__ bv, float* __restrict__ Out) {
  __shared__ _Float16 As[2][64][72];
  __shared__ _Float16 Bs[2][64][72];
  const int tid = threadIdx.x;
  const int wave = tid >> 6, lane = tid & 63;
  const int wr = wave >> 1, wc = wave & 1;
  const int lr16 = lane & 15, kq = lane >> 4;
  const int bm = blockIdx.x;
  const int sr = tid >> 2, sq = tid & 3;

  const _Float16* Ap = Xh + (size_t)(bm * 64 + sr) * D_ + sq * 8;
  const _Float16* Wp = Wh + (size_t)sr * D_ + sq * 8;

  half8 ra0 = *reinterpret_cast<const half8*>(Ap);
  half8 ra1 = *reinterpret_cast<const half8*>(Ap + 32);
  half8 rw0 = *reinterpret_cast<const half8*>(Wp);
  half8 rw1 = *reinterpret_cast<const half8*>(Wp + 32);
  f32x4 acc[2][2] = {};

  *reinterpret_cast<half8*>(&As[0][sr][sq * 8]) = ra0;
  *reinterpret_cast<half8*>(&As[0][sr][32 + sq * 8]) = ra1;
  *reinterpret_cast<half8*>(&Bs[0][sr][sq * 8]) = rw0;
  *reinterpret_cast<half8*>(&Bs[0][sr][32 + sq * 8]) = rw1;
  __syncthreads();

  for (int step = 0; step < 4; ++step) {
    const int cur = step & 1;
    const bool more = (step + 1 < 4);
    if (more) {
      const int kn = (step + 1) << 6;
      ra0 = *reinterpret_cast<const half8*>(Ap + kn);
      ra1 = *reinterpret_cast<const half8*>(Ap + kn + 32);
      rw0 = *reinterpret_cast<const half8*>(Wp + kn);
      rw1 = *reinterpret_cast<const half8*>(Wp + kn + 32);
    }
    half8 af[2][2], bf[2][2];
#pragma unroll
    for (int m = 0; m < 2; ++m)
#pragma unroll
      for (int s = 0; s < 2; ++s)
        af[m][s] = *reinterpret_cast<const half8*>(
            &As[cur][wr * 32 + m * 16 + lr16][s * 32 + kq * 8]);
#pragma unroll
    for (int n = 0; n < 2; ++n)
#pragma unroll
      for (int s = 0; s < 2; ++s)
        bf[n][s] = *reinterpret_cast<const half8*>(
            &Bs[cur][wc * 32 + n * 16 + lr16][s * 32 + kq * 8]);
#pragma unroll
    for (int m = 0; m < 2; ++m)
#pragma unroll
      for (int n = 0; n < 2; ++n)
#pragma unroll
        for (int s = 0; s < 2; ++s)
          acc[m][n] = __builtin_amdgcn_mfma_f32_16x16x32_f16(af[m][s], bf[n][s], acc[m][n], 0, 0, 0);
    if (more) {
      *reinterpret_cast<half8*>(&As[cur ^ 1][sr][sq * 8]) = ra0;
      *reinterpret_cast<half8*>(&As[cur ^ 1][sr][32 + sq * 8]) = ra1;
      *reinterpret_cast<half8*>(&Bs[cur ^ 1][sr][sq * 8]) = rw0;
      *reinterpret_cast<half8*>(&Bs[cur ^ 1][sr][32 + sq * 8]) = rw1;
      __syncthreads();
    }
  }

#pragma unroll
  for (int m = 0; m < 2; ++m) {
#pragma unroll
    for (int n = 0; n < 2; ++n) {
      const int col = wc * 32 + n * 16 + lr16;
      if (col < MOTION_) {
        const float bb = bv[col];
#pragma unroll
        for (int j = 0; j < 4; ++j) {
          const int row = bm * 64 + wr * 32 + m * 16 + kq * 4 + j;
          float v = acc[m][n][j] + bb;
          Out[(size_t)row * MOTION_ + col] = fminf(fmaxf(v, 0.f), 1.f);
        }
      }
    }
  }
}

// ---------------------------------------------------------------------------
// x_h = fp16(shifted_motion @ W_vm.T + b_vm + PE(t%30)).
// ---------------------------------------------------------------------------
__global__ __launch_bounds__(256) void motion_pe(
    const float* __restrict__ TM, const float* __restrict__ Wvm,
    const float* __restrict__ bvm, _Float16* __restrict__ XoutH) {
  const int d = threadIdx.x;
  const int bt = blockIdx.x;
  const int t = bt & (T_ - 1);
  const int b = bt >> 10;
  float acc = bvm[d];
  if (t > 0) {
    const float* mrow = TM + ((size_t)b * T_ + t - 1) * MOTION_;
    const float* wrow = Wvm + (size_t)d * MOTION_;
#pragma unroll
    for (int m = 0; m < MOTION_; ++m) acc += mrow[m] * wrow[m];
  }
  const int pos = t % PERIOD_;
  const int i2 = d >> 1;
  const float div = expf((float)(2 * i2) * (-9.210340371976184f / 256.f));
  const float ang = (float)pos * div;
  acc += (d & 1) ? cosf(ang) : sinf(ang);
  XoutH[(size_t)bt * D_ + d] = (_Float16)acc;
}

// ---------------------------------------------------------------------------
// MFMA self-attention v4: flash split-K (unchanged from r15/16, verified).
// ---------------------------------------------------------------------------
#define RSK_ 72
#define RSV_ 64
__global__ __launch_bounds__(512) void self_attn(
    const _Float16* __restrict__ QKV, float* __restrict__ Opart,
    float* __restrict__ Ml, float* __restrict__ Ll) {
  __shared__ _Float16 Ks[2][64 * RSK_];
  __shared__ _Float16 VTs[2][64 * RSV_];
  __shared__ _Float16 Ps[8][16 * RSK_];
  const int qtb = blockIdx.x >> 1, half = blockIdx.x & 1;
  const int h = blockIdx.y, b = blockIdx.z;
  const int tid = threadIdx.x;
  const int wave = tid >> 6, lane = tid & 63;
  const int lo = lane & 15, hi = lane >> 4;
  const float slope = exp2f(-2.f * (float)(h + 1));
  const int qloc = wave * 16 + lo;
  const int tq = qtb * 128 + qloc;
  const size_t base = (size_t)b * T_ * 768 + h * 64;
  const int sj = tid >> 3, sch = tid & 7;

  half8 qf[2];
#pragma unroll
  for (int s = 0; s < 2; ++s)
    qf[s] = *reinterpret_cast<const half8*>(
        QKV + base + (size_t)(qtb * 128 + qloc) * 768 + s * 32 + hi * 8);

  f32x4 oacc[4] = {};
  float mrun = -1e30f, lrun = 0.f;

  const int nloc = qtb + 1;
  const int kt0 = half * nloc;

  half8 rk, rv;
  {
    const size_t rowoff = base + (size_t)(kt0 * 64 + sj) * 768;
    rk = *reinterpret_cast<const half8*>(QKV + rowoff + 256 + sch * 8);
    rv = *reinterpret_cast<const half8*>(QKV + rowoff + 512 + sch * 8);
    *reinterpret_cast<half8*>(&Ks[0][sj * RSK_ + sch * 8]) = rk;
#pragma unroll
    for (int r = 0; r < 8; ++r) {
      const int d = sch * 8 + r;
      const int sw = ((d & 7) ^ (d >> 3)) << 3;
      VTs[0][d * RSV_ + (sj ^ sw)] = rv[r];
    }
  }
  __syncthreads();

  for (int i = 0; i < nloc; ++i) {
    const int kt = kt0 + i;
    const int cur = i & 1;
    const bool more = (i + 1 < nloc);
    if (more) {
      const size_t rowoff = base + (size_t)((kt + 1) * 64 + sj) * 768;
      rk = *reinterpret_cast<const half8*>(QKV + rowoff + 256 + sch * 8);
      rv = *reinterpret_cast<const half8*>(QKV + rowoff + 512 + sch * 8);
    }

    f32x4 st[4] = {};
    __builtin_amdgcn_s_setprio(1);
#pragma unroll
    for (int f = 0; f < 4; ++f) {
#pragma unroll
      for (int s = 0; s < 2; ++s) {
        const half8 kf = *reinterpret_cast<const half8*>(
            &Ks[cur][(f * 16 + lo) * RSK_ + s * 32 + hi * 8]);
        st[f] = __builtin_amdgcn_mfma_f32_16x16x32_f16(kf, qf[s], st[f], 0, 0, 0);
      }
    }
    __builtin_amdgcn_s_setprio(0);

    float sc[4][4];
    float tmax = -1e30f;
#pragma unroll
    for (int f = 0; f < 4; ++f)
#pragma unroll
      for (int r = 0; r < 4; ++r) {
        const int j = kt * 64 + f * 16 + hi * 4 + r;
        const int rel = tq - j;
        const float v = (rel >= 0)
            ? st[f][r] * 0.125f - slope * (float)(rel / PERIOD_) : -1e30f;
        sc[f][r] = v;
        tmax = fmaxf(tmax, v);
      }
    tmax = fmaxf(tmax, __shfl_xor(tmax, 16, 64));
    tmax = fmaxf(tmax, __shfl_xor(tmax, 32, 64));
    const float mnew = fmaxf(fmaxf(mrun, tmax), -1e20f);
    const float scale = __expf(mrun - mnew);

    float psum = 0.f;
#pragma unroll
    for (int f = 0; f < 4; ++f) {
      half4 ph;
#pragma unroll
      for (int r = 0; r < 4; ++r) {
        const float pv = __expf(sc[f][r] - mnew);
        psum += pv;
        ph[r] = (_Float16)pv;
      }
      *reinterpret_cast<half4*>(&Ps[wave][lo * RSK_ + f * 16 + hi * 4]) = ph;
    }
    psum += __shfl_xor(psum, 16, 64);
    psum += __shfl_xor(psum, 32, 64);
    lrun = lrun * scale + psum;
    mrun = mnew;

    float rsc[4];
#pragma unroll
    for (int r = 0; r < 4; ++r) rsc[r] = __shfl(scale, hi * 4 + r, 64);
#pragma unroll
    for (int nf = 0; nf < 4; ++nf)
#pragma unroll
      for (int r = 0; r < 4; ++r) oacc[nf][r] *= rsc[r];

    __builtin_amdgcn_s_setprio(1);
#pragma unroll
    for (int s = 0; s < 2; ++s) {
      const half8 pf = *reinterpret_cast<const half8*>(
          &Ps[wave][lo * RSK_ + s * 32 + hi * 8]);
#pragma unroll
      for (int nf = 0; nf < 4; ++nf) {
        const int d = nf * 16 + lo;
        const int sw = ((d & 7) ^ (d >> 3)) << 3;
        const half8 vf = *reinterpret_cast<const half8*>(
            &VTs[cur][d * RSV_ + ((s * 32 + hi * 8) ^ sw)]);
        oacc[nf] = __builtin_amdgcn_mfma_f32_16x16x32_f16(pf, vf, oacc[nf], 0, 0, 0);
      }
    }
    __builtin_amdgcn_s_setprio(0);

    if (more) {
      *reinterpret_cast<half8*>(&Ks[cur ^ 1][sj * RSK_ + sch * 8]) = rk;
#pragma unroll
      for (int r = 0; r < 8; ++r) {
        const int d = sch * 8 + r;
        const int sw = ((d & 7) ^ (d >> 3)) << 3;
        VTs[cur ^ 1][d * RSV_ + (sj ^ sw)] = rv[r];
      }
      __syncthreads();
    }
  }

  const size_t rbase = ((size_t)b * H_ + h) * T_;
  const size_t hoff = (size_t)half * PART_;
#pragma unroll
  for (int nf = 0; nf < 4; ++nf)
#pragma unroll
    for (int r = 0; r < 4; ++r) {
      const int q = qtb * 128 + wave * 16 + hi * 4 + r;
      Opart[(hoff + rbase + q) * 64 + nf * 16 + lo] = oacc[nf][r];
    }
  if (hi == 0) {
    const int q = qtb * 128 + wave * 16 + lo;
    Ml[hoff + rbase + q] = mrun;
    Ll[hoff + rbase + q] = lrun;
  }
}

// ---------------------------------------------------------------------------
// Banded cross-attention: 128-thread blocks (256 blocks, fills all CUs).
// ---------------------------------------------------------------------------
__global__ __launch_bounds__(128) void cross_attn(
    const _Float16* __restrict__ Q, const _Float16* __restrict__ KV,
    _Float16* __restrict__ O) {
  const int gid = blockIdx.x * 128 + threadIdx.x;
  const int h = gid & 3;
  const int bt = gid >> 2;
  const int t = bt & (T_ - 1);
  const int b = bt >> 10;

  float q[64];
  const _Float16* qp = Q + (size_t)bt * D_ + h * 64;
#pragma unroll
  for (int d0 = 0; d0 < 64; d0 += 8) {
    const half8 v = *reinterpret_cast<const half8*>(qp + d0);
#pragma unroll
    for (int e = 0; e < 8; ++e) q[d0 + e] = (float)v[e];
  }

  const int j0 = (t - WIN_ > 0) ? t - WIN_ : 0;
  const int j1 = (t + WIN_ < S_ - 1) ? t + WIN_ : S_ - 1;
  const int nj = j1 - j0 + 1;

  float sc[9];
  float mx = -1e30f;
#pragma unroll
  for (int jj = 0; jj < 9; ++jj) {
    if (jj < nj) {
      const _Float16* kp = KV + ((size_t)b * S_ + j0 + jj) * 512 + h * 64;
      float s = 0.f;
#pragma unroll
      for (int d0 = 0; d0 < 64; d0 += 8) {
        const half8 kv = *reinterpret_cast<const half8*>(kp + d0);
#pragma unroll
        for (int e = 0; e < 8; ++e) s += q[d0 + e] * (float)kv[e];
      }
      sc[jj] = s * 0.125f;
      mx = fmaxf(mx, sc[jj]);
    } else {
      sc[jj] = -1e30f;
    }
  }
  float l = 0.f;
  float p[9];
#pragma unroll
  for (int jj = 0; jj < 9; ++jj) { p[jj] = __expf(sc[jj] - mx); l += p[jj]; }
  const float inv = 1.f / l;

  float o[64];
#pragma unroll
  for (int d = 0; d < 64; ++d) o[d] = 0.f;
#pragma unroll
  for (int jj = 0; jj < 9; ++jj) {
    if (jj < nj) {
      const float pj = p[jj] * inv;
      const _Float16* vp = KV + ((size_t)b * S_ + j0 + jj) * 512 + 256 + h * 64;
#pragma unroll
      for (int d0 = 0; d0 < 64; d0 += 8) {
        const half8 vv = *reinterpret_cast<const half8*>(vp + d0);
#pragma unroll
        for (int e = 0; e < 8; ++e) o[d0 + e] += pj * (float)vv[e];
      }
    }
  }
  _Float16* op = O + (size_t)bt * D_ + h * 64;
#pragma unroll
  for (int d = 0; d < 64; ++d) op[d] = (_Float16)o[d];
}

// ---------------------------------------------------------------------------
// x_h = LN(V) * g + b. V already contains branch + residual (fp16).
// One wave per 256-wide row, 4 rows per block. LN math in fp32.
// ---------------------------------------------------------------------------
__global__ __launch_bounds__(256) void ln_h(
    const _Float16* __restrict__ V, const float* __restrict__ g,
    const float* __restrict__ bta, _Float16* __restrict__ OutH) {
  const int wid = threadIdx.x >> 6, lane = threadIdx.x & 63;
  const size_t row = (size_t)blockIdx.x * 4 + wid;
  const _Float16* vp = V + row * D_;
  float v[4];
  float s = 0.f;
#pragma unroll
  for (int k = 0; k < 4; ++k) {
    const int d = lane + k * 64;
    v[k] = (float)vp[d];
    s += v[k];
  }
#pragma unroll
  for (int off = 32; off; off >>= 1) s += __shfl_xor(s, off, 64);
  const float mu = s * (1.f / 256.f);
  float var = 0.f;
#pragma unroll
  for (int k = 0; k < 4; ++k) { const float d = v[k] - mu; var += d * d; }
#pragma unroll
  for (int off = 32; off; off >>= 1) var += __shfl_xor(var, off, 64);
  const float rs = rsqrtf(var * (1.f / 256.f) + 1e-5f);
#pragma unroll
  for (int k = 0; k < 4; ++k) {
    const int d = lane + k * 64;
    OutH[row * D_ + d] = (_Float16)((v[k] - mu) * rs * g[d] + bta[d]);
  }
}

// ---------------------------------------------------------------------------
extern "C" void kernel_launch(void* const* d_in, const int* in_sizes, int n_in,
                              void* d_out, int out_size, void* d_ws, size_t ws_size,
                              hipStream_t stream) {
  (void)in_sizes; (void)n_in; (void)out_size; (void)ws_size;
  const float* hidden = (const float*)d_in[0];
  const float* tmot   = (const float*)d_in[1];
  const float* W_af   = (const float*)d_in[2];
  const float* b_af   = (const float*)d_in[3];
  const float* c1w    = (const float*)d_in[4];
  const float* c1b    = (const float*)d_in[5];
  const float* c2w    = (const float*)d_in[6];
  const float* c2b    = (const float*)d_in[7];
  const float* Wvm    = (const float*)d_in[8];
  const float* bvm    = (const float*)d_in[9];
  const float* sa_in_w  = (const float*)d_in[10];
  const float* sa_in_b  = (const float*)d_in[11];
  const float* sa_out_w = (const float*)d_in[12];
  const float* sa_out_b = (const float*)d_in[13];
  const float* ca_in_w  = (const float*)d_in[14];
  const float* ca_in_b  = (const float*)d_in[15];
  const float* ca_out_w = (const float*)d_in[16];
  const float* ca_out_b = (const float*)d_in[17];
  const float* ln1g = (const float*)d_in[18];
  const float* ln1b = (const float*)d_in[19];
  const float* ln2g = (const float*)d_in[20];
  const float* ln2b = (const float*)d_in[21];
  const float* ln3g = (const float*)d_in[22];
  const float* ln3b = (const float*)d_in[23];
  const float* ff1w = (const float*)d_in[24];
  const float* ff1b = (const float*)d_in[25];
  const float* ff2w = (const float*)d_in[26];
  const float* ff2b = (const float*)d_in[27];
  const float* Wvr  = (const float*)d_in[28];
  const float* bvr  = (const float*)d_in[29];
  float* out = (float*)d_out;

  float* ws = (float*)d_ws;
  const size_t BSD = (size_t)M_ * D_;  // 2,097,152
  _Float16* t1h = (_Float16*)(ws + 2 * BSD);  // fp16 branch(+res) buffer
  _Float16* hb = (_Float16*)(ws + 3 * BSD);
  _Float16* Rh      = hb;               // 3*BSD halves, time-shared
  _Float16* x_h     = hb + 3 * BSD;     // fp16 residual trunk (= LN output)
  _Float16* audio_h = hb + 4 * BSD;
  _Float16* att_h   = hb + 5 * BSD;
  _Float16* wH      = hb + 6 * BSD;     // WH_TOT halves
  _Float16* ckv_h   = Rh + BSD;
  float* Opart = (float*)(wH + WH_TOT);            // 2*PART_*64 floats
  float* Ml    = Opart + (size_t)2 * PART_ * 64;
  float* Ll    = Ml + (size_t)2 * PART_;

  const dim3 blk(256);

  // one-shot fp16 conversion: weights only
  CvtSrc cs;
  cs.p[0] = W_af;
  cs.p[1] = sa_in_w;            cs.p[2] = sa_in_w + 768 * 256;
  cs.p[3] = sa_out_w;           cs.p[4] = sa_out_w + 256 * 256;
  cs.p[5] = ca_in_w;            cs.p[6] = ca_in_w + 768 * 256;
  cs.p[7] = ca_out_w;           cs.p[8] = ca_out_w + 256 * 256;
  cs.p[9] = ff1w;               cs.p[10] = ff1w + 512 * 256;
  cs.p[11] = ff2w;              cs.p[12] = ff2w + 256 * 512;
  cs.p[13] = c1w;               cs.p[14] = c2w;
  cs.p[15] = hidden;            cs.p[16] = Wvr;
  cvt_all<<<dim3(WH_TOT / 256), blk, 0, stream>>>(cs, wH);

  // audio front-end
  gemm_af<<<dim3(M_ / 64, 4), blk, 0, stream>>>(hidden, wH + O_AF, b_af, audio_h,
                                                M_, 256, 768);
  conv_h<<<dim3(128, 4), blk, 0, stream>>>(audio_h, wH + O_CONV1, c1b, t1h, nullptr, 0);
  conv_h<<<dim3(128, 4), blk, 0, stream>>>(t1h, wH + O_CONV2, c2b, audio_h, audio_h, 1);

  // motion embedding + PE (fp16 trunk)
  motion_pe<<<dim3(M_), blk, 0, stream>>>(tmot, Wvm, bvm, x_h);

  for (int l = 0; l < 2; ++l) {
    // self-attention: split-K -> fused merge+out-proj(+residual) -> LN
    gemm_h<<<dim3(M_ / 64, 12), blk, 0, stream>>>(
        x_h, wH + O_SAIN + l * 196608, sa_in_b + l * 768, nullptr, Rh, M_, 768, 256, 0);
    self_attn<<<dim3(T_ / 128 * 2, H_, B_), dim3(512), 0, stream>>>(Rh, Opart, Ml, Ll);
    gemm_sa<<<dim3(M_ / 64, 4), blk, 0, stream>>>(
        Opart, Ml, Ll, wH + O_SAOUT + l * 65536, sa_out_b + l * 256, x_h, t1h);
    ln_h<<<dim3(M_ / 4), blk, 0, stream>>>(t1h, ln1g + l * 256, ln1b + l * 256, x_h);

    // cross-attention: merged q+kv proj -> banded attn -> out-proj(+res) -> LN
    gemm_ca<<<dim3(M_ / 64, 12), blk, 0, stream>>>(
        x_h, audio_h, wH + O_CAIN + l * 196608, ca_in_b + l * 768, Rh, ckv_h);
    cross_attn<<<dim3(M_ * H_ / 128), dim3(128), 0, stream>>>(Rh, ckv_h, att_h);
    gemm_h<<<dim3(M_ / 64, 4), blk, 0, stream>>>(
        att_h, wH + O_CAOUT + l * 65536, ca_out_b + l * 256, x_h, t1h, M_, 256, 256, 0);
    ln_h<<<dim3(M_ / 4), blk, 0, stream>>>(t1h, ln2g + l * 256, ln2b + l * 256, x_h);

    // FFN: ff1(relu) -> ff2(+res) -> LN
    gemm_h<<<dim3(M_ / 64, 8), blk, 0, stream>>>(
        x_h, wH + O_FF1 + l * 131072, ff1b + l * 512, nullptr, Rh, M_, 512, 256, 1);
    gemm_h<<<dim3(M_ / 64, 4), blk, 0, stream>>>(
        Rh, wH + O_FF2 + l * 131072, ff2b + l * 256, x_h, t1h, M_, 256, 512, 0);
    ln_h<<<dim3(M_ / 4), blk, 0, stream>>>(t1h, ln3g + l * 256, ln3b + l * 256, x_h);
  }

  head_mfma<<<dim3(M_ / 64), blk, 0, stream>>>(x_h, wH + O_VR, bvr, out);
}

// Round 18
// 315.303 us; speedup vs baseline: 1.0158x; 1.0158x over previous
//
#include <hip/hip_runtime.h>
#include <math.h>

#define B_ 8
#define T_ 1024
#define S_ 1024
#define D_ 256
#define H_ 4
#define DH_ 64
#define AUDIO_ 768
#define MOTION_ 33
#define PERIOD_ 30
#define WIN_ 4
#define M_ (B_ * T_)
#define PART_ (B_ * H_ * T_)   // 32768 partial rows per half

typedef _Float16 half8 __attribute__((ext_vector_type(8)));
typedef _Float16 half4 __attribute__((ext_vector_type(4)));
typedef __attribute__((ext_vector_type(4))) float f32x4;

// fp16 weight arena offsets (halves)
#define O_AF    0
#define O_SAIN  196608   // + l*196608
#define O_SAOUT 589824   // + l*65536
#define O_CAIN  720896   // + l*196608
#define O_CAOUT 1114112  // + l*65536
#define O_FF1   1245184  // + l*131072
#define O_FF2   1507328  // + l*131072
#define O_CONV1 1769472
#define O_CONV2 2097152
#define O_VR    2424832  // W_vr padded to 64x256
#define WH_TOT  2441216  // divisible by 256 -> exact grid

struct CvtSrc { const float* p[17]; };

// ---------------------------------------------------------------------------
// One-shot fp32->fp16 conversion of all weights (+ conv repack, + W_vr pad).
// hidden_states is NOT converted (gemm_af reads fp32 directly).
// ---------------------------------------------------------------------------
__global__ __launch_bounds__(256) void cvt_all(
    CvtSrc s, _Float16* __restrict__ wH) {
  const long i = (long)blockIdx.x * 256 + threadIdx.x;
  if (i >= WH_TOT) return;
  if (i >= O_VR) {
    const long j = i - O_VR, oc = j >> 8, cin = j & 255;
    wH[i] = (oc < MOTION_) ? (_Float16)s.p[16][oc * 256 + cin] : (_Float16)0.f;
    return;
  }
  if (i >= O_CONV2) {
    const long j = i - O_CONV2, oc = j / 1280, r = j % 1280, tap = r >> 8, cin = r & 255;
    wH[i] = (_Float16)s.p[14][(oc * 256 + cin) * 5 + tap]; return;
  }
  if (i >= O_CONV1) {
    const long j = i - O_CONV1, oc = j / 1280, r = j % 1280, tap = r >> 8, cin = r & 255;
    wH[i] = (_Float16)s.p[13][(oc * 256 + cin) * 5 + tap]; return;
  }
  int seg; long base;
  if      (i >= 1638400) { seg = 12; base = 1638400; }
  else if (i >= 1507328) { seg = 11; base = 1507328; }
  else if (i >= 1376256) { seg = 10; base = 1376256; }
  else if (i >= 1245184) { seg = 9;  base = 1245184; }
  else if (i >= 1179648) { seg = 8;  base = 1179648; }
  else if (i >= 1114112) { seg = 7;  base = 1114112; }
  else if (i >= 917504)  { seg = 6;  base = 917504; }
  else if (i >= 720896)  { seg = 5;  base = 720896; }
  else if (i >= 655360)  { seg = 4;  base = 655360; }
  else if (i >= 589824)  { seg = 3;  base = 589824; }
  else if (i >= 393216)  { seg = 2;  base = 393216; }
  else if (i >= 196608)  { seg = 1;  base = 196608; }
  else                   { seg = 0;  base = 0; }
  wH[i] = (_Float16)s.p[seg][i - base];
}

// ---------------------------------------------------------------------------
// fp16 GEMM: C = A @ W.T + bias. Tile 64x64, BK=64, LDS double-buffer,
// one barrier per K-step. Outputs: Cf fp32 (nullable), Ch fp16 (nullable).
// ---------------------------------------------------------------------------
__global__ __launch_bounds__(256) void gemm_h(
    const _Float16* __restrict__ A, const _Float16* __restrict__ W,
    const float* __restrict__ bias, float* __restrict__ Cf,
    _Float16* __restrict__ Ch, int M, int N, int K, int relu) {
  __shared__ _Float16 As[2][64][72];
  __shared__ _Float16 Bs[2][64][72];
  const int tid = threadIdx.x;
  const int wave = tid >> 6, lane = tid & 63;
  const int wr = wave >> 1, wc = wave & 1;
  const int lr16 = lane & 15, kq = lane >> 4;
  const int bm = blockIdx.x, bn = blockIdx.y;
  const int sr = tid >> 2, sq = tid & 3;

  const _Float16* Ap = A + (size_t)(bm * 64 + sr) * K + sq * 8;
  const _Float16* Wp = W + (size_t)(bn * 64 + sr) * K + sq * 8;

  half8 ra0 = *reinterpret_cast<const half8*>(Ap);
  half8 ra1 = *reinterpret_cast<const half8*>(Ap + 32);
  half8 rw0 = *reinterpret_cast<const half8*>(Wp);
  half8 rw1 = *reinterpret_cast<const half8*>(Wp + 32);
  f32x4 acc[2][2] = {};

  *reinterpret_cast<half8*>(&As[0][sr][sq * 8]) = ra0;
  *reinterpret_cast<half8*>(&As[0][sr][32 + sq * 8]) = ra1;
  *reinterpret_cast<half8*>(&Bs[0][sr][sq * 8]) = rw0;
  *reinterpret_cast<half8*>(&Bs[0][sr][32 + sq * 8]) = rw1;
  __syncthreads();

  const int nsteps = K >> 6;
  for (int step = 0; step < nsteps; ++step) {
    const int cur = step & 1;
    const bool more = (step + 1 < nsteps);
    if (more) {
      const int kn = (step + 1) << 6;
      ra0 = *reinterpret_cast<const half8*>(Ap + kn);
      ra1 = *reinterpret_cast<const half8*>(Ap + kn + 32);
      rw0 = *reinterpret_cast<const half8*>(Wp + kn);
      rw1 = *reinterpret_cast<const half8*>(Wp + kn + 32);
    }
    half8 af[2][2], bf[2][2];
#pragma unroll
    for (int m = 0; m < 2; ++m)
#pragma unroll
      for (int s = 0; s < 2; ++s)
        af[m][s] = *reinterpret_cast<const half8*>(
            &As[cur][wr * 32 + m * 16 + lr16][s * 32 + kq * 8]);
#pragma unroll
    for (int n = 0; n < 2; ++n)
#pragma unroll
      for (int s = 0; s < 2; ++s)
        bf[n][s] = *reinterpret_cast<const half8*>(
            &Bs[cur][wc * 32 + n * 16 + lr16][s * 32 + kq * 8]);
#pragma unroll
    for (int m = 0; m < 2; ++m)
#pragma unroll
      for (int n = 0; n < 2; ++n)
#pragma unroll
        for (int s = 0; s < 2; ++s)
          acc[m][n] = __builtin_amdgcn_mfma_f32_16x16x32_f16(af[m][s], bf[n][s], acc[m][n], 0, 0, 0);
    if (more) {
      *reinterpret_cast<half8*>(&As[cur ^ 1][sr][sq * 8]) = ra0;
      *reinterpret_cast<half8*>(&As[cur ^ 1][sr][32 + sq * 8]) = ra1;
      *reinterpret_cast<half8*>(&Bs[cur ^ 1][sr][sq * 8]) = rw0;
      *reinterpret_cast<half8*>(&Bs[cur ^ 1][sr][32 + sq * 8]) = rw1;
      __syncthreads();
    }
  }

#pragma unroll
  for (int m = 0; m < 2; ++m) {
#pragma unroll
    for (int n = 0; n < 2; ++n) {
      const int col = bn * 64 + wc * 32 + n * 16 + lr16;
      const float bv = bias[col];
#pragma unroll
      for (int j = 0; j < 4; ++j) {
        const int row = bm * 64 + wr * 32 + m * 16 + kq * 4 + j;
        float v = acc[m][n][j] + bv;
        if (relu) v = fmaxf(v, 0.f);
        const size_t idx = (size_t)row * N + col;
        if (Cf) Cf[idx] = v;
        if (Ch) Ch[idx] = (_Float16)v;
      }
    }
  }
}

// ---------------------------------------------------------------------------
// Audio front-end GEMM with fp32 A (converts in staging regs). C fp16 only.
// ---------------------------------------------------------------------------
__global__ __launch_bounds__(256) void gemm_af(
    const float* __restrict__ A, const _Float16* __restrict__ W,
    const float* __restrict__ bias, _Float16* __restrict__ Ch,
    int M, int N, int K) {
  __shared__ _Float16 As[2][64][72];
  __shared__ _Float16 Bs[2][64][72];
  const int tid = threadIdx.x;
  const int wave = tid >> 6, lane = tid & 63;
  const int wr = wave >> 1, wc = wave & 1;
  const int lr16 = lane & 15, kq = lane >> 4;
  const int bm = blockIdx.x, bn = blockIdx.y;
  const int sr = tid >> 2, sq = tid & 3;

  const float* Ap = A + (size_t)(bm * 64 + sr) * K + sq * 8;
  const _Float16* Wp = W + (size_t)(bn * 64 + sr) * K + sq * 8;

  float4 fa0, fa1, fa2, fa3;
  half8 rw0, rw1;
  fa0 = *reinterpret_cast<const float4*>(Ap);
  fa1 = *reinterpret_cast<const float4*>(Ap + 4);
  fa2 = *reinterpret_cast<const float4*>(Ap + 32);
  fa3 = *reinterpret_cast<const float4*>(Ap + 36);
  rw0 = *reinterpret_cast<const half8*>(Wp);
  rw1 = *reinterpret_cast<const half8*>(Wp + 32);
  f32x4 acc[2][2] = {};

  {
    half8 pa0, pa1;
    pa0[0] = (_Float16)fa0.x; pa0[1] = (_Float16)fa0.y; pa0[2] = (_Float16)fa0.z; pa0[3] = (_Float16)fa0.w;
    pa0[4] = (_Float16)fa1.x; pa0[5] = (_Float16)fa1.y; pa0[6] = (_Float16)fa1.z; pa0[7] = (_Float16)fa1.w;
    pa1[0] = (_Float16)fa2.x; pa1[1] = (_Float16)fa2.y; pa1[2] = (_Float16)fa2.z; pa1[3] = (_Float16)fa2.w;
    pa1[4] = (_Float16)fa3.x; pa1[5] = (_Float16)fa3.y; pa1[6] = (_Float16)fa3.z; pa1[7] = (_Float16)fa3.w;
    *reinterpret_cast<half8*>(&As[0][sr][sq * 8]) = pa0;
    *reinterpret_cast<half8*>(&As[0][sr][32 + sq * 8]) = pa1;
    *reinterpret_cast<half8*>(&Bs[0][sr][sq * 8]) = rw0;
    *reinterpret_cast<half8*>(&Bs[0][sr][32 + sq * 8]) = rw1;
  }
  __syncthreads();

  const int nsteps = K >> 6;
  for (int step = 0; step < nsteps; ++step) {
    const int cur = step & 1;
    const bool more = (step + 1 < nsteps);
    if (more) {
      const int kn = (step + 1) << 6;
      fa0 = *reinterpret_cast<const float4*>(Ap + kn);
      fa1 = *reinterpret_cast<const float4*>(Ap + kn + 4);
      fa2 = *reinterpret_cast<const float4*>(Ap + kn + 32);
      fa3 = *reinterpret_cast<const float4*>(Ap + kn + 36);
      rw0 = *reinterpret_cast<const half8*>(Wp + kn);
      rw1 = *reinterpret_cast<const half8*>(Wp + kn + 32);
    }
    half8 af[2][2], bf[2][2];
#pragma unroll
    for (int m = 0; m < 2; ++m)
#pragma unroll
      for (int s = 0; s < 2; ++s)
        af[m][s] = *reinterpret_cast<const half8*>(
            &As[cur][wr * 32 + m * 16 + lr16][s * 32 + kq * 8]);
#pragma unroll
    for (int n = 0; n < 2; ++n)
#pragma unroll
      for (int s = 0; s < 2; ++s)
        bf[n][s] = *reinterpret_cast<const half8*>(
            &Bs[cur][wc * 32 + n * 16 + lr16][s * 32 + kq * 8]);
#pragma unroll
    for (int m = 0; m < 2; ++m)
#pragma unroll
      for (int n = 0; n < 2; ++n)
#pragma unroll
        for (int s = 0; s < 2; ++s)
          acc[m][n] = __builtin_amdgcn_mfma_f32_16x16x32_f16(af[m][s], bf[n][s], acc[m][n], 0, 0, 0);
    if (more) {
      half8 pa0, pa1;
      pa0[0] = (_Float16)fa0.x; pa0[1] = (_Float16)fa0.y; pa0[2] = (_Float16)fa0.z; pa0[3] = (_Float16)fa0.w;
      pa0[4] = (_Float16)fa1.x; pa0[5] = (_Float16)fa1.y; pa0[6] = (_Float16)fa1.z; pa0[7] = (_Float16)fa1.w;
      pa1[0] = (_Float16)fa2.x; pa1[1] = (_Float16)fa2.y; pa1[2] = (_Float16)fa2.z; pa1[3] = (_Float16)fa2.w;
      pa1[4] = (_Float16)fa3.x; pa1[5] = (_Float16)fa3.y; pa1[6] = (_Float16)fa3.z; pa1[7] = (_Float16)fa3.w;
      *reinterpret_cast<half8*>(&As[cur ^ 1][sr][sq * 8]) = pa0;
      *reinterpret_cast<half8*>(&As[cur ^ 1][sr][32 + sq * 8]) = pa1;
      *reinterpret_cast<half8*>(&Bs[cur ^ 1][sr][sq * 8]) = rw0;
      *reinterpret_cast<half8*>(&Bs[cur ^ 1][sr][32 + sq * 8]) = rw1;
      __syncthreads();
    }
  }

#pragma unroll
  for (int m = 0; m < 2; ++m) {
#pragma unroll
    for (int n = 0; n < 2; ++n) {
      const int col = bn * 64 + wc * 32 + n * 16 + lr16;
      const float bv = bias[col];
#pragma unroll
      for (int j = 0; j < 4; ++j) {
        const int row = bm * 64 + wr * 32 + m * 16 + kq * 4 + j;
        Ch[(size_t)row * N + col] = (_Float16)(acc[m][n][j] + bv);
      }
    }
  }
}

// ---------------------------------------------------------------------------
// SA out-projection with FUSED split-K merge: A-operand K-chunk s == head s,
// so staging reads the two fp32 partials + (m,l) for h = step, merges in
// registers, and ds_writes merged fp16 directly. M = 8192, N = 256, K = 256.
// ---------------------------------------------------------------------------
struct SaPre {
  float4 h0a, h0b, h0c, h0d;   // half0: ch sq*8 (a,b) and 32+sq*8 (c,d)
  float4 h1a, h1b, h1c, h1d;   // half1
  float m0, m1, l0, l1;
};

__device__ __forceinline__ SaPre sa_load(
    const float* __restrict__ Opart, const float* __restrict__ Ml,
    const float* __restrict__ Ll, size_t p, int sq) {
  SaPre x;
  const float* o0 = Opart + p * 64;
  const float* o1 = Opart + (size_t)PART_ * 64 + p * 64;
  x.h0a = *reinterpret_cast<const float4*>(o0 + sq * 8);
  x.h0b = *reinterpret_cast<const float4*>(o0 + sq * 8 + 4);
  x.h0c = *reinterpret_cast<const float4*>(o0 + 32 + sq * 8);
  x.h0d = *reinterpret_cast<const float4*>(o0 + 36 + sq * 8);
  x.h1a = *reinterpret_cast<const float4*>(o1 + sq * 8);
  x.h1b = *reinterpret_cast<const float4*>(o1 + sq * 8 + 4);
  x.h1c = *reinterpret_cast<const float4*>(o1 + 32 + sq * 8);
  x.h1d = *reinterpret_cast<const float4*>(o1 + 36 + sq * 8);
  x.m0 = Ml[p]; x.m1 = Ml[(size_t)PART_ + p];
  x.l0 = Ll[p]; x.l1 = Ll[(size_t)PART_ + p];
  return x;
}

__device__ __forceinline__ void sa_write(
    _Float16* dst0, _Float16* dst1, const SaPre& x) {
  const float m = fmaxf(x.m0, x.m1);
  const float w0 = __expf(x.m0 - m), w1 = __expf(x.m1 - m);
  const float inv = 1.f / (x.l0 * w0 + x.l1 * w1);
  const float g0h0[8] = {x.h0a.x, x.h0a.y, x.h0a.z, x.h0a.w,
                         x.h0b.x, x.h0b.y, x.h0b.z, x.h0b.w};
  const float g0h1[8] = {x.h1a.x, x.h1a.y, x.h1a.z, x.h1a.w,
                         x.h1b.x, x.h1b.y, x.h1b.z, x.h1b.w};
  const float g1h0[8] = {x.h0c.x, x.h0c.y, x.h0c.z, x.h0c.w,
                         x.h0d.x, x.h0d.y, x.h0d.z, x.h0d.w};
  const float g1h1[8] = {x.h1c.x, x.h1c.y, x.h1c.z, x.h1c.w,
                         x.h1d.x, x.h1d.y, x.h1d.z, x.h1d.w};
  half8 pa, pb;
#pragma unroll
  for (int e = 0; e < 8; ++e) {
    pa[e] = (_Float16)((g0h0[e] * w0 + g0h1[e] * w1) * inv);
    pb[e] = (_Float16)((g1h0[e] * w0 + g1h1[e] * w1) * inv);
  }
  *reinterpret_cast<half8*>(dst0) = pa;
  *reinterpret_cast<half8*>(dst1) = pb;
}

__global__ __launch_bounds__(256) void gemm_sa(
    const float* __restrict__ Opart, const float* __restrict__ Ml,
    const float* __restrict__ Ll, const _Float16* __restrict__ W,
    const float* __restrict__ bias, _Float16* __restrict__ Ch) {
  __shared__ _Float16 As[2][64][72];
  __shared__ _Float16 Bs[2][64][72];
  const int tid = threadIdx.x;
  const int wave = tid >> 6, lane = tid & 63;
  const int wr = wave >> 1, wc = wave & 1;
  const int lr16 = lane & 15, kq = lane >> 4;
  const int bm = blockIdx.x, bn = blockIdx.y;
  const int sr = tid >> 2, sq = tid & 3;

  const int r = bm * 64 + sr;                       // global row = b*1024+t
  const size_t pb0 = (size_t)(r >> 10) * 4096 + (r & 1023);  // + h*1024
  const _Float16* Wp = W + (size_t)(bn * 64 + sr) * 256 + sq * 8;

  SaPre ax = sa_load(Opart, Ml, Ll, pb0, sq);       // h = 0
  half8 rw0 = *reinterpret_cast<const half8*>(Wp);
  half8 rw1 = *reinterpret_cast<const half8*>(Wp + 32);
  f32x4 acc[2][2] = {};

  sa_write(&As[0][sr][sq * 8], &As[0][sr][32 + sq * 8], ax);
  *reinterpret_cast<half8*>(&Bs[0][sr][sq * 8]) = rw0;
  *reinterpret_cast<half8*>(&Bs[0][sr][32 + sq * 8]) = rw1;
  __syncthreads();

  for (int step = 0; step < 4; ++step) {
    const int cur = step & 1;
    const bool more = (step + 1 < 4);
    if (more) {
      ax = sa_load(Opart, Ml, Ll, pb0 + (size_t)(step + 1) * 1024, sq);
      const int kn = (step + 1) << 6;
      rw0 = *reinterpret_cast<const half8*>(Wp + kn);
      rw1 = *reinterpret_cast<const half8*>(Wp + kn + 32);
    }
    half8 af[2][2], bf[2][2];
#pragma unroll
    for (int m = 0; m < 2; ++m)
#pragma unroll
      for (int s = 0; s < 2; ++s)
        af[m][s] = *reinterpret_cast<const half8*>(
            &As[cur][wr * 32 + m * 16 + lr16][s * 32 + kq * 8]);
#pragma unroll
    for (int n = 0; n < 2; ++n)
#pragma unroll
      for (int s = 0; s < 2; ++s)
        bf[n][s] = *reinterpret_cast<const half8*>(
            &Bs[cur][wc * 32 + n * 16 + lr16][s * 32 + kq * 8]);
#pragma unroll
    for (int m = 0; m < 2; ++m)
#pragma unroll
      for (int n = 0; n < 2; ++n)
#pragma unroll
        for (int s = 0; s < 2; ++s)
          acc[m][n] = __builtin_amdgcn_mfma_f32_16x16x32_f16(af[m][s], bf[n][s], acc[m][n], 0, 0, 0);
    if (more) {
      sa_write(&As[cur ^ 1][sr][sq * 8], &As[cur ^ 1][sr][32 + sq * 8], ax);
      *reinterpret_cast<half8*>(&Bs[cur ^ 1][sr][sq * 8]) = rw0;
      *reinterpret_cast<half8*>(&Bs[cur ^ 1][sr][32 + sq * 8]) = rw1;
      __syncthreads();
    }
  }

#pragma unroll
  for (int m = 0; m < 2; ++m) {
#pragma unroll
    for (int n = 0; n < 2; ++n) {
      const int col = bn * 64 + wc * 32 + n * 16 + lr16;
      const float bv = bias[col];
#pragma unroll
      for (int j = 0; j < 4; ++j) {
        const int row = bm * 64 + wr * 32 + m * 16 + kq * 4 + j;
        Ch[(size_t)row * 256 + col] = (_Float16)(acc[m][n][j] + bv);
      }
    }
  }
}

// ---------------------------------------------------------------------------
// Merged cross-attention projections: one dispatch, grid (M/64, 12).
// ---------------------------------------------------------------------------
__global__ __launch_bounds__(256) void gemm_ca(
    const _Float16* __restrict__ Aq, const _Float16* __restrict__ Akv,
    const _Float16* __restrict__ W, const float* __restrict__ bias,
    _Float16* __restrict__ Oq, _Float16* __restrict__ Okv) {
  __shared__ _Float16 As[2][64][72];
  __shared__ _Float16 Bs[2][64][72];
  const int tid = threadIdx.x;
  const int wave = tid >> 6, lane = tid & 63;
  const int wr = wave >> 1, wc = wave & 1;
  const int lr16 = lane & 15, kq = lane >> 4;
  const int bm = blockIdx.x, bn = blockIdx.y;
  const int sr = tid >> 2, sq = tid & 3;
  const bool isq = (bn < 4);
  const _Float16* A = isq ? Aq : Akv;
  _Float16* Optr = isq ? Oq : Okv;
  const int Nout = isq ? 256 : 512;
  const int ocol0 = (isq ? bn : bn - 4) * 64;

  const _Float16* Ap = A + (size_t)(bm * 64 + sr) * 256 + sq * 8;
  const _Float16* Wp = W + (size_t)(bn * 64 + sr) * 256 + sq * 8;

  half8 ra0 = *reinterpret_cast<const half8*>(Ap);
  half8 ra1 = *reinterpret_cast<const half8*>(Ap + 32);
  half8 rw0 = *reinterpret_cast<const half8*>(Wp);
  half8 rw1 = *reinterpret_cast<const half8*>(Wp + 32);
  f32x4 acc[2][2] = {};

  *reinterpret_cast<half8*>(&As[0][sr][sq * 8]) = ra0;
  *reinterpret_cast<half8*>(&As[0][sr][32 + sq * 8]) = ra1;
  *reinterpret_cast<half8*>(&Bs[0][sr][sq * 8]) = rw0;
  *reinterpret_cast<half8*>(&Bs[0][sr][32 + sq * 8]) = rw1;
  __syncthreads();

  for (int step = 0; step < 4; ++step) {
    const int cur = step & 1;
    const bool more = (step + 1 < 4);
    if (more) {
      const int kn = (step + 1) << 6;
      ra0 = *reinterpret_cast<const half8*>(Ap + kn);
      ra1 = *reinterpret_cast<const half8*>(Ap + kn + 32);
      rw0 = *reinterpret_cast<const half8*>(Wp + kn);
      rw1 = *reinterpret_cast<const half8*>(Wp + kn + 32);
    }
    half8 af[2][2], bf[2][2];
#pragma unroll
    for (int m = 0; m < 2; ++m)
#pragma unroll
      for (int s = 0; s < 2; ++s)
        af[m][s] = *reinterpret_cast<const half8*>(
            &As[cur][wr * 32 + m * 16 + lr16][s * 32 + kq * 8]);
#pragma unroll
    for (int n = 0; n < 2; ++n)
#pragma unroll
      for (int s = 0; s < 2; ++s)
        bf[n][s] = *reinterpret_cast<const half8*>(
            &Bs[cur][wc * 32 + n * 16 + lr16][s * 32 + kq * 8]);
#pragma unroll
    for (int m = 0; m < 2; ++m)
#pragma unroll
      for (int n = 0; n < 2; ++n)
#pragma unroll
        for (int s = 0; s < 2; ++s)
          acc[m][n] = __builtin_amdgcn_mfma_f32_16x16x32_f16(af[m][s], bf[n][s], acc[m][n], 0, 0, 0);
    if (more) {
      *reinterpret_cast<half8*>(&As[cur ^ 1][sr][sq * 8]) = ra0;
      *reinterpret_cast<half8*>(&As[cur ^ 1][sr][32 + sq * 8]) = ra1;
      *reinterpret_cast<half8*>(&Bs[cur ^ 1][sr][sq * 8]) = rw0;
      *reinterpret_cast<half8*>(&Bs[cur ^ 1][sr][32 + sq * 8]) = rw1;
      __syncthreads();
    }
  }

#pragma unroll
  for (int m = 0; m < 2; ++m) {
#pragma unroll
    for (int n = 0; n < 2; ++n) {
      const int lc = wc * 32 + n * 16 + lr16;
      const float bv = bias[bn * 64 + lc];
#pragma unroll
      for (int j = 0; j < 4; ++j) {
        const int row = bm * 64 + wr * 32 + m * 16 + kq * 4 + j;
        Optr[(size_t)row * Nout + ocol0 + lc] = (_Float16)(acc[m][n][j] + bv);
      }
    }
  }
}

// ---------------------------------------------------------------------------
// Conv1d k=5 as fp16 GEMM, K=1280 tap-major repacked weights, BK=64, dbuf.
// ---------------------------------------------------------------------------
__device__ __forceinline__ half8 conv_ld(const _Float16* Xb, int p, int tap, int cin) {
  const int sp = p + tap - 2;
  if (sp < 0 || sp >= S_) { half8 z = {}; return z; }
  return *reinterpret_cast<const half8*>(Xb + (size_t)sp * D_ + cin);
}

__global__ __launch_bounds__(256) void conv_h(
    const _Float16* __restrict__ Xh, const _Float16* __restrict__ Wc,
    const float* __restrict__ bias, _Float16* OutH,
    const _Float16* ResH, int mode) {
  __shared__ _Float16 As[2][64][72];
  __shared__ _Float16 Bs[2][64][72];
  const int tid = threadIdx.x;
  const int wave = tid >> 6, lane = tid & 63;
  const int wr = wave >> 1, wc = wave & 1;
  const int lr16 = lane & 15, kq = lane >> 4;
  const int b = blockIdx.x >> 4;
  const int s0 = (blockIdx.x & 15) * 64;
  const int o0 = blockIdx.y * 64;
  const int sr = tid >> 2, sq = tid & 3;

  const _Float16* Xb = Xh + (size_t)b * S_ * D_;
  const _Float16* Wp = Wc + (size_t)(o0 + sr) * 1280 + sq * 8;
  const int p = s0 + sr;

  half8 ra0 = conv_ld(Xb, p, 0, sq * 8);
  half8 ra1 = conv_ld(Xb, p, 0, 32 + sq * 8);
  half8 rw0 = *reinterpret_cast<const half8*>(Wp);
  half8 rw1 = *reinterpret_cast<const half8*>(Wp + 32);
  f32x4 acc[2][2] = {};

  *reinterpret_cast<half8*>(&As[0][sr][sq * 8]) = ra0;
  *reinterpret_cast<half8*>(&As[0][sr][32 + sq * 8]) = ra1;
  *reinterpret_cast<half8*>(&Bs[0][sr][sq * 8]) = rw0;
  *reinterpret_cast<half8*>(&Bs[0][sr][32 + sq * 8]) = rw1;
  __syncthreads();

  for (int step = 0; step < 20; ++step) {
    const int cur = step & 1;
    const bool more = (step + 1 < 20);
    if (more) {
      const int kn = (step + 1) << 6;
      const int tap = kn >> 8, cb = kn & 255;
      ra0 = conv_ld(Xb, p, tap, cb + sq * 8);
      ra1 = conv_ld(Xb, p, tap, cb + 32 + sq * 8);
      rw0 = *reinterpret_cast<const half8*>(Wp + kn);
      rw1 = *reinterpret_cast<const half8*>(Wp + kn + 32);
    }
    half8 af[2][2], bf[2][2];
#pragma unroll
    for (int m = 0; m < 2; ++m)
#pragma unroll
      for (int s = 0; s < 2; ++s)
        af[m][s] = *reinterpret_cast<const half8*>(
            &As[cur][wr * 32 + m * 16 + lr16][s * 32 + kq * 8]);
#pragma unroll
    for (int n = 0; n < 2; ++n)
#pragma unroll
      for (int s = 0; s < 2; ++s)
        bf[n][s] = *reinterpret_cast<const half8*>(
            &Bs[cur][wc * 32 + n * 16 + lr16][s * 32 + kq * 8]);
#pragma unroll
    for (int m = 0; m < 2; ++m)
#pragma unroll
      for (int n = 0; n < 2; ++n)
#pragma unroll
        for (int s = 0; s < 2; ++s)
          acc[m][n] = __builtin_amdgcn_mfma_f32_16x16x32_f16(af[m][s], bf[n][s], acc[m][n], 0, 0, 0);
    if (more) {
      *reinterpret_cast<half8*>(&As[cur ^ 1][sr][sq * 8]) = ra0;
      *reinterpret_cast<half8*>(&As[cur ^ 1][sr][32 + sq * 8]) = ra1;
      *reinterpret_cast<half8*>(&Bs[cur ^ 1][sr][sq * 8]) = rw0;
      *reinterpret_cast<half8*>(&Bs[cur ^ 1][sr][32 + sq * 8]) = rw1;
      __syncthreads();
    }
  }

#pragma unroll
  for (int m = 0; m < 2; ++m) {
#pragma unroll
    for (int n = 0; n < 2; ++n) {
      const int oc = o0 + wc * 32 + n * 16 + lr16;
      const float bv = bias[oc];
#pragma unroll
      for (int j = 0; j < 4; ++j) {
        const int s = s0 + wr * 32 + m * 16 + kq * 4 + j;
        const size_t idx = ((size_t)b * S_ + s) * D_ + oc;
        float v = acc[m][n][j] + bv;
        if (mode == 0) {
          v = 0.5f * v * (1.f + erff(v * 0.70710678118654752f));
        } else {
          v += (float)ResH[idx];
        }
        OutH[idx] = (_Float16)v;
      }
    }
  }
}

// ---------------------------------------------------------------------------
// Head: out = clip(x @ W_vr.T + b_vr, 0, 1) via MFMA (W_vr padded to 64).
// ---------------------------------------------------------------------------
__global__ __launch_bounds__(256) void head_mfma(
    const _Float16* __restrict__ Xh, const _Float16* __restrict__ Wh,
    const float* __restrict__ bv, float* __restrict__ Out) {
  __shared__ _Float16 As[2][64][72];
  __shared__ _Float16 Bs[2][64][72];
  const int tid = threadIdx.x;
  const int wave = tid >> 6, lane = tid & 63;
  const int wr = wave >> 1, wc = wave & 1;
  const int lr16 = lane & 15, kq = lane >> 4;
  const int bm = blockIdx.x;
  const int sr = tid >> 2, sq = tid & 3;

  const _Float16* Ap = Xh + (size_t)(bm * 64 + sr) * D_ + sq * 8;
  const _Float16* Wp = Wh + (size_t)sr * D_ + sq * 8;

  half8 ra0 = *reinterpret_cast<const half8*>(Ap);
  half8 ra1 = *reinterpret_cast<const half8*>(Ap + 32);
  half8 rw0 = *reinterpret_cast<const half8*>(Wp);
  half8 rw1 = *reinterpret_cast<const half8*>(Wp + 32);
  f32x4 acc[2][2] = {};

  *reinterpret_cast<half8*>(&As[0][sr][sq * 8]) = ra0;
  *reinterpret_cast<half8*>(&As[0][sr][32 + sq * 8]) = ra1;
  *reinterpret_cast<half8*>(&Bs[0][sr][sq * 8]) = rw0;
  *reinterpret_cast<half8*>(&Bs[0][sr][32 + sq * 8]) = rw1;
  __syncthreads();

  for (int step = 0; step < 4; ++step) {
    const int cur = step & 1;
    const bool more = (step + 1 < 4);
    if (more) {
      const int kn = (step + 1) << 6;
      ra0 = *reinterpret_cast<const half8*>(Ap + kn);
      ra1 = *reinterpret_cast<const half8*>(Ap + kn + 32);
      rw0 = *reinterpret_cast<const half8*>(Wp + kn);
      rw1 = *reinterpret_cast<const half8*>(Wp + kn + 32);
    }
    half8 af[2][2], bf[2][2];
#pragma unroll
    for (int m = 0; m < 2; ++m)
#pragma unroll
      for (int s = 0; s < 2; ++s)
        af[m][s] = *reinterpret_cast<const half8*>(
            &As[cur][wr * 32 + m * 16 + lr16][s * 32 + kq * 8]);
#pragma unroll
    for (int n = 0; n < 2; ++n)
#pragma unroll
      for (int s = 0; s < 2; ++s)
        bf[n][s] = *reinterpret_cast<const half8*>(
            &Bs[cur][wc * 32 + n * 16 + lr16][s * 32 + kq * 8]);
#pragma unroll
    for (int m = 0; m < 2; ++m)
#pragma unroll
      for (int n = 0; n < 2; ++n)
#pragma unroll
        for (int s = 0; s < 2; ++s)
          acc[m][n] = __builtin_amdgcn_mfma_f32_16x16x32_f16(af[m][s], bf[n][s], acc[m][n], 0, 0, 0);
    if (more) {
      *reinterpret_cast<half8*>(&As[cur ^ 1][sr][sq * 8]) = ra0;
      *reinterpret_cast<half8*>(&As[cur ^ 1][sr][32 + sq * 8]) = ra1;
      *reinterpret_cast<half8*>(&Bs[cur ^ 1][sr][sq * 8]) = rw0;
      *reinterpret_cast<half8*>(&Bs[cur ^ 1][sr][32 + sq * 8]) = rw1;
      __syncthreads();
    }
  }

#pragma unroll
  for (int m = 0; m < 2; ++m) {
#pragma unroll
    for (int n = 0; n < 2; ++n) {
      const int col = wc * 32 + n * 16 + lr16;
      if (col < MOTION_) {
        const float bb = bv[col];
#pragma unroll
        for (int j = 0; j < 4; ++j) {
          const int row = bm * 64 + wr * 32 + m * 16 + kq * 4 + j;
          float v = acc[m][n][j] + bb;
          Out[(size_t)row * MOTION_ + col] = fminf(fmaxf(v, 0.f), 1.f);
        }
      }
    }
  }
}

// ---------------------------------------------------------------------------
// x = shifted_motion @ W_vm.T + b_vm + PE(t%30); writes fp32 + fp16 mirror.
// ---------------------------------------------------------------------------
__global__ __launch_bounds__(256) void motion_pe(
    const float* __restrict__ TM, const float* __restrict__ Wvm,
    const float* __restrict__ bvm, float* __restrict__ Xout,
    _Float16* __restrict__ XoutH) {
  const int d = threadIdx.x;
  const int bt = blockIdx.x;
  const int t = bt & (T_ - 1);
  const int b = bt >> 10;
  float acc = bvm[d];
  if (t > 0) {
    const float* mrow = TM + ((size_t)b * T_ + t - 1) * MOTION_;
    const float* wrow = Wvm + (size_t)d * MOTION_;
#pragma unroll
    for (int m = 0; m < MOTION_; ++m) acc += mrow[m] * wrow[m];
  }
  const int pos = t % PERIOD_;
  const int i2 = d >> 1;
  const float div = expf((float)(2 * i2) * (-9.210340371976184f / 256.f));
  const float ang = (float)pos * div;
  acc += (d & 1) ? cosf(ang) : sinf(ang);
  Xout[(size_t)bt * D_ + d] = acc;
  XoutH[(size_t)bt * D_ + d] = (_Float16)acc;
}

// ---------------------------------------------------------------------------
// MFMA self-attention v4: flash split-K (verified r15/16).
// ---------------------------------------------------------------------------
#define RSK_ 72
#define RSV_ 64
__global__ __launch_bounds__(512) void self_attn(
    const _Float16* __restrict__ QKV, float* __restrict__ Opart,
    float* __restrict__ Ml, float* __restrict__ Ll) {
  __shared__ _Float16 Ks[2][64 * RSK_];
  __shared__ _Float16 VTs[2][64 * RSV_];
  __shared__ _Float16 Ps[8][16 * RSK_];
  const int qtb = blockIdx.x >> 1, half = blockIdx.x & 1;
  const int h = blockIdx.y, b = blockIdx.z;
  const int tid = threadIdx.x;
  const int wave = tid >> 6, lane = tid & 63;
  const int lo = lane & 15, hi = lane >> 4;
  const float slope = exp2f(-2.f * (float)(h + 1));
  const int qloc = wave * 16 + lo;
  const int tq = qtb * 128 + qloc;
  const size_t base = (size_t)b * T_ * 768 + h * 64;
  const int sj = tid >> 3, sch = tid & 7;

  half8 qf[2];
#pragma unroll
  for (int s = 0; s < 2; ++s)
    qf[s] = *reinterpret_cast<const half8*>(
        QKV + base + (size_t)(qtb * 128 + qloc) * 768 + s * 32 + hi * 8);

  f32x4 oacc[4] = {};
  float mrun = -1e30f, lrun = 0.f;

  const int nloc = qtb + 1;
  const int kt0 = half * nloc;

  half8 rk, rv;
  {
    const size_t rowoff = base + (size_t)(kt0 * 64 + sj) * 768;
    rk = *reinterpret_cast<const half8*>(QKV + rowoff + 256 + sch * 8);
    rv = *reinterpret_cast<const half8*>(QKV + rowoff + 512 + sch * 8);
    *reinterpret_cast<half8*>(&Ks[0][sj * RSK_ + sch * 8]) = rk;
#pragma unroll
    for (int r = 0; r < 8; ++r) {
      const int d = sch * 8 + r;
      const int sw = ((d & 7) ^ (d >> 3)) << 3;
      VTs[0][d * RSV_ + (sj ^ sw)] = rv[r];
    }
  }
  __syncthreads();

  for (int i = 0; i < nloc; ++i) {
    const int kt = kt0 + i;
    const int cur = i & 1;
    const bool more = (i + 1 < nloc);
    if (more) {
      const size_t rowoff = base + (size_t)((kt + 1) * 64 + sj) * 768;
      rk = *reinterpret_cast<const half8*>(QKV + rowoff + 256 + sch * 8);
      rv = *reinterpret_cast<const half8*>(QKV + rowoff + 512 + sch * 8);
    }

    f32x4 st[4] = {};
    __builtin_amdgcn_s_setprio(1);
#pragma unroll
    for (int f = 0; f < 4; ++f) {
#pragma unroll
      for (int s = 0; s < 2; ++s) {
        const half8 kf = *reinterpret_cast<const half8*>(
            &Ks[cur][(f * 16 + lo) * RSK_ + s * 32 + hi * 8]);
        st[f] = __builtin_amdgcn_mfma_f32_16x16x32_f16(kf, qf[s], st[f], 0, 0, 0);
      }
    }
    __builtin_amdgcn_s_setprio(0);

    float sc[4][4];
    float tmax = -1e30f;
#pragma unroll
    for (int f = 0; f < 4; ++f)
#pragma unroll
      for (int r = 0; r < 4; ++r) {
        const int j = kt * 64 + f * 16 + hi * 4 + r;
        const int rel = tq - j;
        const float v = (rel >= 0)
            ? st[f][r] * 0.125f - slope * (float)(rel / PERIOD_) : -1e30f;
        sc[f][r] = v;
        tmax = fmaxf(tmax, v);
      }
    tmax = fmaxf(tmax, __shfl_xor(tmax, 16, 64));
    tmax = fmaxf(tmax, __shfl_xor(tmax, 32, 64));
    const float mnew = fmaxf(fmaxf(mrun, tmax), -1e20f);
    const float scale = __expf(mrun - mnew);

    float psum = 0.f;
#pragma unroll
    for (int f = 0; f < 4; ++f) {
      half4 ph;
#pragma unroll
      for (int r = 0; r < 4; ++r) {
        const float pv = __expf(sc[f][r] - mnew);
        psum += pv;
        ph[r] = (_Float16)pv;
      }
      *reinterpret_cast<half4*>(&Ps[wave][lo * RSK_ + f * 16 + hi * 4]) = ph;
    }
    psum += __shfl_xor(psum, 16, 64);
    psum += __shfl_xor(psum, 32, 64);
    lrun = lrun * scale + psum;
    mrun = mnew;

    float rsc[4];
#pragma unroll
    for (int r = 0; r < 4; ++r) rsc[r] = __shfl(scale, hi * 4 + r, 64);
#pragma unroll
    for (int nf = 0; nf < 4; ++nf)
#pragma unroll
      for (int r = 0; r < 4; ++r) oacc[nf][r] *= rsc[r];

    __builtin_amdgcn_s_setprio(1);
#pragma unroll
    for (int s = 0; s < 2; ++s) {
      const half8 pf = *reinterpret_cast<const half8*>(
          &Ps[wave][lo * RSK_ + s * 32 + hi * 8]);
#pragma unroll
      for (int nf = 0; nf < 4; ++nf) {
        const int d = nf * 16 + lo;
        const int sw = ((d & 7) ^ (d >> 3)) << 3;
        const half8 vf = *reinterpret_cast<const half8*>(
            &VTs[cur][d * RSV_ + ((s * 32 + hi * 8) ^ sw)]);
        oacc[nf] = __builtin_amdgcn_mfma_f32_16x16x32_f16(pf, vf, oacc[nf], 0, 0, 0);
      }
    }
    __builtin_amdgcn_s_setprio(0);

    if (more) {
      *reinterpret_cast<half8*>(&Ks[cur ^ 1][sj * RSK_ + sch * 8]) = rk;
#pragma unroll
      for (int r = 0; r < 8; ++r) {
        const int d = sch * 8 + r;
        const int sw = ((d & 7) ^ (d >> 3)) << 3;
        VTs[cur ^ 1][d * RSV_ + (sj ^ sw)] = rv[r];
      }
      __syncthreads();
    }
  }

  const size_t rbase = ((size_t)b * H_ + h) * T_;
  const size_t hoff = (size_t)half * PART_;
#pragma unroll
  for (int nf = 0; nf < 4; ++nf)
#pragma unroll
    for (int r = 0; r < 4; ++r) {
      const int q = qtb * 128 + wave * 16 + hi * 4 + r;
      Opart[(hoff + rbase + q) * 64 + nf * 16 + lo] = oacc[nf][r];
    }
  if (hi == 0) {
    const int q = qtb * 128 + wave * 16 + lo;
    Ml[hoff + rbase + q] = mrun;
    Ll[hoff + rbase + q] = lrun;
  }
}

// ---------------------------------------------------------------------------
// Banded cross-attention: 128-thread blocks (256 blocks, fills all CUs).
// ---------------------------------------------------------------------------
__global__ __launch_bounds__(128) void cross_attn(
    const _Float16* __restrict__ Q, const _Float16* __restrict__ KV,
    _Float16* __restrict__ O) {
  const int gid = blockIdx.x * 128 + threadIdx.x;
  const int h = gid & 3;
  const int bt = gid >> 2;
  const int t = bt & (T_ - 1);
  const int b = bt >> 10;

  float q[64];
  const _Float16* qp = Q + (size_t)bt * D_ + h * 64;
#pragma unroll
  for (int d0 = 0; d0 < 64; d0 += 8) {
    const half8 v = *reinterpret_cast<const half8*>(qp + d0);
#pragma unroll
    for (int e = 0; e < 8; ++e) q[d0 + e] = (float)v[e];
  }

  const int j0 = (t - WIN_ > 0) ? t - WIN_ : 0;
  const int j1 = (t + WIN_ < S_ - 1) ? t + WIN_ : S_ - 1;
  const int nj = j1 - j0 + 1;

  float sc[9];
  float mx = -1e30f;
#pragma unroll
  for (int jj = 0; jj < 9; ++jj) {
    if (jj < nj) {
      const _Float16* kp = KV + ((size_t)b * S_ + j0 + jj) * 512 + h * 64;
      float s = 0.f;
#pragma unroll
      for (int d0 = 0; d0 < 64; d0 += 8) {
        const half8 kv = *reinterpret_cast<const half8*>(kp + d0);
#pragma unroll
        for (int e = 0; e < 8; ++e) s += q[d0 + e] * (float)kv[e];
      }
      sc[jj] = s * 0.125f;
      mx = fmaxf(mx, sc[jj]);
    } else {
      sc[jj] = -1e30f;
    }
  }
  float l = 0.f;
  float p[9];
#pragma unroll
  for (int jj = 0; jj < 9; ++jj) { p[jj] = __expf(sc[jj] - mx); l += p[jj]; }
  const float inv = 1.f / l;

  float o[64];
#pragma unroll
  for (int d = 0; d < 64; ++d) o[d] = 0.f;
#pragma unroll
  for (int jj = 0; jj < 9; ++jj) {
    if (jj < nj) {
      const float pj = p[jj] * inv;
      const _Float16* vp = KV + ((size_t)b * S_ + j0 + jj) * 512 + 256 + h * 64;
#pragma unroll
      for (int d0 = 0; d0 < 64; d0 += 8) {
        const half8 vv = *reinterpret_cast<const half8*>(vp + d0);
#pragma unroll
        for (int e = 0; e < 8; ++e) o[d0 + e] += pj * (float)vv[e];
      }
    }
  }
  _Float16* op = O + (size_t)bt * D_ + h * 64;
#pragma unroll
  for (int d = 0; d < 64; ++d) op[d] = (_Float16)o[d];
}

// ---------------------------------------------------------------------------
// Out = LayerNorm(X + R) * g + b; R is fp16; writes fp32 trunk + fp16 mirror.
// ---------------------------------------------------------------------------
__global__ __launch_bounds__(256) void ln_res(
    const float* X, const _Float16* __restrict__ R,
    const float* __restrict__ g, const float* __restrict__ bta,
    float* Out, _Float16* __restrict__ OutH) {
  const int wid = threadIdx.x >> 6, lane = threadIdx.x & 63;
  const size_t row = (size_t)blockIdx.x * 4 + wid;
  const float* xp = X + row * D_;
  const _Float16* rp = R + row * D_;
  float v[4];
  float s = 0.f;
#pragma unroll
  for (int k = 0; k < 4; ++k) {
    const int d = lane + k * 64;
    v[k] = xp[d] + (float)rp[d];
    s += v[k];
  }
#pragma unroll
  for (int off = 32; off; off >>= 1) s += __shfl_xor(s, off, 64);
  const float mu = s * (1.f / 256.f);
  float var = 0.f;
#pragma unroll
  for (int k = 0; k < 4; ++k) { const float d = v[k] - mu; var += d * d; }
#pragma unroll
  for (int off = 32; off; off >>= 1) var += __shfl_xor(var, off, 64);
  const float rs = rsqrtf(var * (1.f / 256.f) + 1e-5f);
#pragma unroll
  for (int k = 0; k < 4; ++k) {
    const int d = lane + k * 64;
    const float o = (v[k] - mu) * rs * g[d] + bta[d];
    Out[row * D_ + d] = o;
    OutH[row * D_ + d] = (_Float16)o;
  }
}

// ---------------------------------------------------------------------------
extern "C" void kernel_launch(void* const* d_in, const int* in_sizes, int n_in,
                              void* d_out, int out_size, void* d_ws, size_t ws_size,
                              hipStream_t stream) {
  (void)in_sizes; (void)n_in; (void)out_size; (void)ws_size;
  const float* hidden = (const float*)d_in[0];
  const float* tmot   = (const float*)d_in[1];
  const float* W_af   = (const float*)d_in[2];
  const float* b_af   = (const float*)d_in[3];
  const float* c1w    = (const float*)d_in[4];
  const float* c1b    = (const float*)d_in[5];
  const float* c2w    = (const float*)d_in[6];
  const float* c2b    = (const float*)d_in[7];
  const float* Wvm    = (const float*)d_in[8];
  const float* bvm    = (const float*)d_in[9];
  const float* sa_in_w  = (const float*)d_in[10];
  const float* sa_in_b  = (const float*)d_in[11];
  const float* sa_out_w = (const float*)d_in[12];
  const float* sa_out_b = (const float*)d_in[13];
  const float* ca_in_w  = (const float*)d_in[14];
  const float* ca_in_b  = (const float*)d_in[15];
  const float* ca_out_w = (const float*)d_in[16];
  const float* ca_out_b = (const float*)d_in[17];
  const float* ln1g = (const float*)d_in[18];
  const float* ln1b = (const float*)d_in[19];
  const float* ln2g = (const float*)d_in[20];
  const float* ln2b = (const float*)d_in[21];
  const float* ln3g = (const float*)d_in[22];
  const float* ln3b = (const float*)d_in[23];
  const float* ff1w = (const float*)d_in[24];
  const float* ff1b = (const float*)d_in[25];
  const float* ff2w = (const float*)d_in[26];
  const float* ff2b = (const float*)d_in[27];
  const float* Wvr  = (const float*)d_in[28];
  const float* bvr  = (const float*)d_in[29];
  float* out = (float*)d_out;

  float* ws = (float*)d_ws;
  const size_t BSD = (size_t)M_ * D_;  // 2,097,152
  float* x     = ws + BSD;              // fp32 residual trunk
  _Float16* t1h = (_Float16*)(ws + 2 * BSD);  // fp16 branch output
  _Float16* hb = (_Float16*)(ws + 3 * BSD);
  _Float16* Rh      = hb;               // 3*BSD halves, time-shared
  _Float16* x_h     = hb + 3 * BSD;
  _Float16* audio_h = hb + 4 * BSD;
  _Float16* att_h   = hb + 5 * BSD;
  _Float16* wH      = hb + 6 * BSD;     // WH_TOT halves
  _Float16* ckv_h   = Rh + BSD;
  // split-K attention partials (fp32), after the weight arena
  float* Opart = (float*)(wH + WH_TOT);            // 2*PART_*64 floats
  float* Ml    = Opart + (size_t)2 * PART_ * 64;   // 2*PART_
  float* Ll    = Ml + (size_t)2 * PART_;           // 2*PART_

  const dim3 blk(256);

  // one-shot fp16 conversion: weights only (hidden handled by gemm_af)
  CvtSrc cs;
  cs.p[0] = W_af;
  cs.p[1] = sa_in_w;            cs.p[2] = sa_in_w + 768 * 256;
  cs.p[3] = sa_out_w;           cs.p[4] = sa_out_w + 256 * 256;
  cs.p[5] = ca_in_w;            cs.p[6] = ca_in_w + 768 * 256;
  cs.p[7] = ca_out_w;           cs.p[8] = ca_out_w + 256 * 256;
  cs.p[9] = ff1w;               cs.p[10] = ff1w + 512 * 256;
  cs.p[11] = ff2w;              cs.p[12] = ff2w + 256 * 512;
  cs.p[13] = c1w;               cs.p[14] = c2w;
  cs.p[15] = hidden;            cs.p[16] = Wvr;
  cvt_all<<<dim3(WH_TOT / 256), blk, 0, stream>>>(cs, wH);

  // audio front-end (gemm_af converts fp32 hidden in staging)
  gemm_af<<<dim3(M_ / 64, 4), blk, 0, stream>>>(hidden, wH + O_AF, b_af, audio_h,
                                                M_, 256, 768);
  conv_h<<<dim3(128, 4), blk, 0, stream>>>(audio_h, wH + O_CONV1, c1b, t1h, nullptr, 0);
  conv_h<<<dim3(128, 4), blk, 0, stream>>>(t1h, wH + O_CONV2, c2b, audio_h, audio_h, 1);

  // motion embedding + PE
  motion_pe<<<dim3(M_), blk, 0, stream>>>(tmot, Wvm, bvm, x, x_h);

  for (int l = 0; l < 2; ++l) {
    // self-attention: split-K -> fused merge+out-proj
    gemm_h<<<dim3(M_ / 64, 12), blk, 0, stream>>>(
        x_h, wH + O_SAIN + l * 196608, sa_in_b + l * 768, nullptr, Rh, M_, 768, 256, 0);
    self_attn<<<dim3(T_ / 128 * 2, H_, B_), dim3(512), 0, stream>>>(Rh, Opart, Ml, Ll);
    gemm_sa<<<dim3(M_ / 64, 4), blk, 0, stream>>>(
        Opart, Ml, Ll, wH + O_SAOUT + l * 65536, sa_out_b + l * 256, t1h);
    ln_res<<<dim3(M_ / 4), blk, 0, stream>>>(x, t1h, ln1g + l * 256, ln1b + l * 256, x, x_h);

    // cross-attention (banded): merged q+kv projection, one dispatch
    gemm_ca<<<dim3(M_ / 64, 12), blk, 0, stream>>>(
        x_h, audio_h, wH + O_CAIN + l * 196608, ca_in_b + l * 768, Rh, ckv_h);
    cross_attn<<<dim3(M_ * H_ / 128), dim3(128), 0, stream>>>(Rh, ckv_h, att_h);
    gemm_h<<<dim3(M_ / 64, 4), blk, 0, stream>>>(
        att_h, wH + O_CAOUT + l * 65536, ca_out_b + l * 256, nullptr, t1h, M_, 256, 256, 0);
    ln_res<<<dim3(M_ / 4), blk, 0, stream>>>(x, t1h, ln2g + l * 256, ln2b + l * 256, x, x_h);

    // FFN
    gemm_h<<<dim3(M_ / 64, 8), blk, 0, stream>>>(
        x_h, wH + O_FF1 + l * 131072, ff1b + l * 512, nullptr, Rh, M_, 512, 256, 1);
    gemm_h<<<dim3(M_ / 64, 4), blk, 0, stream>>>(
        Rh, wH + O_FF2 + l * 131072, ff2b + l * 256, nullptr, t1h, M_, 256, 512, 0);
    ln_res<<<dim3(M_ / 4), blk, 0, stream>>>(x, t1h, ln3g + l * 256, ln3b + l * 256, x, x_h);
  }

  head_mfma<<<dim3(M_ / 64), blk, 0, stream>>>(x_h, wH + O_VR, bvr, out);
}